// Round 5
// baseline (3932.943 us; speedup 1.0000x reference)
//
#include <hip/hip_runtime.h>

#define BATCH 16
#define CH 512
#define OC 1536
#define KDIM 1024
#define LMAX 4096
#define WGLOB_SZ 6291456  // 32 kc * 1536 rows * 128 B

typedef __attribute__((ext_vector_type(8))) short s8v;
typedef __attribute__((ext_vector_type(4))) float f4v;

__device__ __forceinline__ int nfp2_of(int n) { return 1 << (31 - __clz(n)); }

__device__ __forceinline__ unsigned short f2bf(float x) {
  union { float f; unsigned u; } v; v.f = x;
  unsigned r = v.u + 0x7fffu + ((v.u >> 16) & 1u);
  return (unsigned short)(r >> 16);
}
__device__ __forceinline__ float bf2f(unsigned short b) {
  union { unsigned u; float f; } v; v.u = ((unsigned)b) << 16; return v.f;
}
__device__ __forceinline__ void hilo(float x, unsigned short& hi, unsigned short& lo) {
  hi = f2bf(x);
  lo = f2bf(x - bf2f(hi));
}

// per-batch arena layout (device-computed from Nvec)
__device__ __forceinline__ void layout(const int* __restrict__ Nvec, int b,
                                       size_t& offC0, size_t& offA, size_t& offB,
                                       int& n, int& nfp2, int& half) {
  size_t c0t = 0, at = 0, bt = 0, c0o = 0, ao = 0, bo = 0;
  n = 2; nfp2 = 2; half = 0;
#pragma unroll 1
  for (int i = 0; i < BATCH; ++i) {
    int ni = Nvec[i];
    int f = nfp2_of(ni);
    int hf = ni - f;
    size_t cs = (size_t)((hf + 127) & ~127) << 12;
    size_t as = (size_t)(f >> 1) << 12;
    size_t bs = (size_t)(f >> 2) << 12;
    if (i < b) { c0o += cs; ao += as; bo += bs; }
    if (i == b) { n = ni; nfp2 = f; half = hf; }
    c0t += cs; at += as; bt += bs;
  }
  offC0 = (size_t)WGLOB_SZ + c0o;
  offA = (size_t)WGLOB_SZ + c0t + ao;
  offB = (size_t)WGLOB_SZ + c0t + at + bo;
}

__device__ __forceinline__ void gload16(const void* g, void* l) {
  __builtin_amdgcn_global_load_lds((const __attribute__((address_space(1))) void*)g,
                                   (__attribute__((address_space(3))) void*)l, 16, 0, 0);
}

// ---------- W prep: W[o][k] fp32 -> Wglob[kc][o][hi 32bf16 | lo 32bf16] ----------
__global__ __launch_bounds__(256) void prep_w_k(const float* __restrict__ W, char* __restrict__ ws) {
  int idx = blockIdx.x * 256 + threadIdx.x;  // idx = kc*1536 + o
  if (idx >= 32 * 1536) return;
  int kc = idx / 1536;
  int o = idx - kc * 1536;
  const float* src = W + (size_t)o * KDIM + kc * 32;
  unsigned short hb[32], lb[32];
#pragma unroll
  for (int t = 0; t < 32; ++t) hilo(src[t], hb[t], lb[t]);
  uint4* d4 = (uint4*)(ws + ((size_t)idx << 7));
#pragma unroll
  for (int q = 0; q < 4; ++q) {
    uint4 v;
    v.x = (unsigned)hb[q*8+0] | ((unsigned)hb[q*8+1] << 16);
    v.y = (unsigned)hb[q*8+2] | ((unsigned)hb[q*8+3] << 16);
    v.z = (unsigned)hb[q*8+4] | ((unsigned)hb[q*8+5] << 16);
    v.w = (unsigned)hb[q*8+6] | ((unsigned)hb[q*8+7] << 16);
    d4[q] = v;
  }
#pragma unroll
  for (int q = 0; q < 4; ++q) {
    uint4 v;
    v.x = (unsigned)lb[q*8+0] | ((unsigned)lb[q*8+1] << 16);
    v.y = (unsigned)lb[q*8+2] | ((unsigned)lb[q*8+3] << 16);
    v.z = (unsigned)lb[q*8+4] | ((unsigned)lb[q*8+5] << 16);
    v.w = (unsigned)lb[q*8+6] | ((unsigned)lb[q*8+7] << 16);
    d4[4 + q] = v;
  }
}

// ---------- h reorg: coalesced read + LDS transpose ----------
__global__ __launch_bounds__(256) void reorg_h_k(const float* __restrict__ h,
                                                 const int* __restrict__ Nvec,
                                                 char* __restrict__ ws,
                                                 float* __restrict__ dout, int mode) {
  __shared__ char T[32 * 512];  // 16 KB
  const int b = blockIdx.z;
  size_t offC0, offA, offB; int n, nfp2, half;
  layout(Nvec, b, offC0, offA, offB, n, nfp2, half);
  const int tid = threadIdx.x;
  const int c0 = blockIdx.y * 64;

  if (mode == 1 && nfp2 == 1) {  // degenerate: answer is h[:, 0]
    if (blockIdx.x == 0 && tid < 64)
      dout[(size_t)b * CH + c0 + tid] = h[(size_t)b * CH * LMAX + (size_t)(c0 + tid) * LMAX];
    return;
  }

  const int d0 = blockIdx.x * 32;
  int dlo, dhi, soff;
  size_t base;
  if (mode == 0) { dlo = 0; dhi = half; soff = 0; base = offC0; }
  else { dlo = half >> 1; dhi = nfp2 >> 1; soff = half; base = offA; }
  if (d0 >= dhi || d0 + 32 <= dlo) return;

  const float* hb = h + (size_t)b * CH * LMAX;

#pragma unroll
  for (int q = 0; q < 8; ++q) {
    int id = q * 256 + tid;
    int cl = id >> 5;
    int dl = id & 31;
    int d = d0 + dl;
    bool ok = (d < dhi) && (d >= dlo);
    float2 v;
    v.x = 0.f; v.y = 0.f;
    if (ok) v = *(const float2*)(hb + (size_t)(c0 + cl) * LMAX + 2 * d + soff);
    unsigned short h0, l0_, h1, l1_;
    hilo(v.x, h0, l0_);
    hilo(v.y, h1, l1_);
    int g = cl >> 2;
    int byte_hi = dl * 512 + ((g ^ (dl & 15)) << 4) + (cl & 3) * 4;
    *(unsigned*)(T + byte_hi) = (unsigned)h0 | ((unsigned)h1 << 16);
    *(unsigned*)(T + byte_hi + 256) = (unsigned)l0_ | ((unsigned)l1_ << 16);
  }
  __syncthreads();
#pragma unroll
  for (int qq = 0; qq < 4; ++qq) {
    int gid = qq * 256 + tid;
    int dl = gid >> 5;
    int hl = (gid >> 4) & 1;
    int seg = gid & 15;
    int d = d0 + dl;
    if (d >= dhi || d < dlo) continue;
    uint4 val = *(const uint4*)(T + dl * 512 + hl * 256 + ((seg ^ (dl & 15)) << 4));
    *(uint4*)(ws + base + ((size_t)d << 12) + (hl << 11) + (size_t)c0 * 4 + seg * 16) = val;
  }
}

// ---------- one reduction level: split-bf16 MFMA GEMM + fused gate ----------
// 192x256 tile, 512 threads, 8 waves = 2 row-groups (3 parts x 32 ch) x 4 col-groups.
// Single-buffer LDS (57 KB) -> 2 blocks/CU for cross-block stage/compute overlap.
// Block id remap: the 8 o0-groups of one col-tile get ids == same (mod 8) -> same XCD,
// so a B col-tile is fetched into one XCD's L2 once and hit 7 times.
__global__ __launch_bounds__(512, 4) void mfma_level_k(const float* __restrict__ bias,
                                                       const int* __restrict__ Nvec,
                                                       char* __restrict__ ws,
                                                       float* __restrict__ dout,
                                                       int level, int tiles) {
  __shared__ char smem[57344];  // As 24576 + Bs 32768
  const int id = blockIdx.x;
  const int g8 = (id >> 3) & 7;                 // o0 group
  const int t = ((id >> 6) << 3) | (id & 7);    // global tile index = b*tiles + xb
  const int o0 = g8 * 64;
  const int xb = t % tiles;
  const int b = t / tiles;
  if (b >= BATCH) return;

  size_t offC0, offA, offB; int n, nfp2, half;
  layout(Nvec, b, offC0, offA, offB, n, nfp2, half);

  int cols;
  size_t inOff, outOff;
  if (level == 0) {
    if (half == 0) return;
    cols = half;
    inOff = offC0;
    outOff = offA;
  } else {
    int w = nfp2 >> (level - 1);
    if (w < 2) return;
    cols = w >> 1;
    inOff = (level & 1) ? offA : offB;
    outOff = (level & 1) ? offB : offA;
  }
  const bool fin = (level > 0) && ((nfp2 >> level) == 1);
  const int l0 = xb * 256;
  if (l0 >= cols) return;

  const int tid = threadIdx.x;
  const int lane = tid & 63, wid = tid >> 6;
  const int lane15 = lane & 15, lq = lane >> 4;
  const int rg = wid & 1, cg = wid >> 1;
  const char* inp = ws + inOff;

  // staging offsets (kc-independent parts)
  unsigned aoff[3]; int adst[3];
#pragma unroll
  for (int q = 0; q < 3; ++q) {
    int d = q * 8192 + tid * 16;
    int r = d >> 7;
    int p = (d >> 4) & 7;
    int o = ((r >> 6) << 9) + o0 + (r & 63);
    int g = p ^ (r & 7);
    aoff[q] = ((unsigned)o << 7) + (g << 4);
    adst[q] = q * 8192 + wid * 1024;
  }
  unsigned boff[4]; int bdst[4];
#pragma unroll
  for (int q = 0; q < 4; ++q) {
    int d = q * 8192 + tid * 16;
    int l = d >> 7;
    int p = (d >> 4) & 7;
    int lc = l0 + l; if (lc > cols - 1) lc = cols - 1;
    int g = p ^ (l & 7);
    boff[q] = ((unsigned)lc << 12) + ((unsigned)(g >> 2) << 11) + ((g & 3) << 4);
    bdst[q] = q * 8192 + wid * 1024;
  }

#define STAGE(kc) do {                                                       \
    char* Ab = smem;                                                         \
    char* Bb = smem + 24576;                                                 \
    unsigned ka = (unsigned)(kc) * (1536u << 7);                             \
    unsigned kb = (unsigned)(kc) << 6;                                       \
    _Pragma("unroll") for (int q = 0; q < 3; ++q)                            \
      gload16(ws + ka + aoff[q], Ab + adst[q]);                              \
    _Pragma("unroll") for (int q = 0; q < 4; ++q)                            \
      gload16(inp + kb + boff[q], Bb + bdst[q]);                             \
  } while (0)

  f4v acc[6][4];
#pragma unroll
  for (int m = 0; m < 6; ++m)
#pragma unroll
    for (int cf = 0; cf < 4; ++cf) acc[m][cf] = (f4v){0.f, 0.f, 0.f, 0.f};

#pragma unroll 1
  for (int kc = 0; kc < 32; ++kc) {
    STAGE(kc);
    __syncthreads();
    const char* Asb = smem;
    const char* Bsb = smem + 24576;

    s8v bh[4], bl[4];
#pragma unroll
    for (int cf = 0; cf < 4; ++cf) {
      int ll = cg * 64 + cf * 16 + lane15;
      int ph = lq ^ (ll & 7);
      int pl = (4 + lq) ^ (ll & 7);
      bh[cf] = *(const s8v*)(Bsb + ll * 128 + ph * 16);
      bl[cf] = *(const s8v*)(Bsb + ll * 128 + pl * 16);
    }
#pragma unroll
    for (int m = 0; m < 6; ++m) {
      int rr = (m >> 1) * 64 + rg * 32 + (m & 1) * 16 + lane15;
      s8v ah = *(const s8v*)(Asb + rr * 128 + ((lq ^ (rr & 7)) << 4));
      s8v al = *(const s8v*)(Asb + rr * 128 + (((4 + lq) ^ (rr & 7)) << 4));
#pragma unroll
      for (int cf = 0; cf < 4; ++cf) {
        acc[m][cf] = __builtin_amdgcn_mfma_f32_16x16x32_bf16(ah, bh[cf], acc[m][cf], 0, 0, 0);
        acc[m][cf] = __builtin_amdgcn_mfma_f32_16x16x32_bf16(ah, bl[cf], acc[m][cf], 0, 0, 0);
        acc[m][cf] = __builtin_amdgcn_mfma_f32_16x16x32_bf16(al, bh[cf], acc[m][cf], 0, 0, 0);
      }
    }
    __syncthreads();
  }
#undef STAGE

  // epilogue: gate in registers, store bf16 hi/lo pair-major (or final fp32)
  char* outp = ws + outOff;
#pragma unroll
  for (int s = 0; s < 2; ++s) {
#pragma unroll
    for (int cf = 0; cf < 4; ++cf) {
      f4v vl = acc[s][cf], vr = acc[2 + s][cf], vg = acc[4 + s][cf];
      int l = l0 + cg * 64 + cf * 16 + lane15;
      if (l >= cols) continue;
#pragma unroll
      for (int j = 0; j < 4; ++j) {
        int c = o0 + rg * 32 + s * 16 + lq * 4 + j;
        float zl = vl[j] + bias[c];
        float zr = vr[j] + bias[CH + c];
        float zg = vg[j] + bias[2 * CH + c];
        float g = 1.f / (1.f + __expf(-zg));
        float rt = 1.f - 2.f / (1.f + __expf(2.f * zr));
        float val = zl * g + rt * (1.f - g);
        if (fin) {
          if (l == 0) dout[(size_t)b * CH + c] = val;
        } else {
          unsigned short hi, lo; hilo(val, hi, lo);
          char* orow = outp + ((size_t)(l >> 1) << 12) + ((size_t)(2 * c + (l & 1)) << 1);
          *(unsigned short*)(orow) = hi;
          *(unsigned short*)(orow + 2048) = lo;
        }
      }
    }
  }
}

extern "C" void kernel_launch(void* const* d_in, const int* in_sizes, int n_in,
                              void* d_out, int out_size, void* d_ws, size_t ws_size,
                              hipStream_t stream) {
  const float* h = (const float*)d_in[0];
  const float* W = (const float*)d_in[1];
  const float* bias = (const float*)d_in[2];
  const int* Nvec = (const int*)d_in[3];
  float* dout = (float*)d_out;
  char* ws = (char*)d_ws;

  prep_w_k<<<dim3(192), 256, 0, stream>>>(W, ws);
  reorg_h_k<<<dim3(64, 8, BATCH), 256, 0, stream>>>(h, Nvec, ws, dout, 0);
  reorg_h_k<<<dim3(64, 8, BATCH), 256, 0, stream>>>(h, Nvec, ws, dout, 1);

  // level 0: max half = 952 -> 4 tiles of 256
  mfma_level_k<<<dim3(4 * 8 * BATCH), 512, 0, stream>>>(bias, Nvec, ws, dout, 0, 4);
  for (int lev = 1; lev <= 12; ++lev) {
    int colsmax = LMAX >> lev;               // worst-case cols at this level
    int tiles = (colsmax + 255) / 256; if (tiles < 1) tiles = 1;
    mfma_level_k<<<dim3(tiles * 8 * BATCH), 512, 0, stream>>>(bias, Nvec, ws, dout, lev, tiles);
  }
}

// Round 6
// 1103.091 us; speedup vs baseline: 3.5654x; 3.5654x over previous
//
#include <hip/hip_runtime.h>

#define BATCH 16
#define CH 512
#define OC 1536
#define KDIM 1024
#define LMAX 4096
#define WGLOB_SZ 6291456  // 32 kc * 1536 rows * 128 B

typedef __attribute__((ext_vector_type(8))) short s8v;
typedef __attribute__((ext_vector_type(4))) float f4v;

__device__ __forceinline__ int nfp2_of(int n) { return 1 << (31 - __clz(n)); }

__device__ __forceinline__ unsigned short f2bf(float x) {
  union { float f; unsigned u; } v; v.f = x;
  unsigned r = v.u + 0x7fffu + ((v.u >> 16) & 1u);
  return (unsigned short)(r >> 16);
}
__device__ __forceinline__ float bf2f(unsigned short b) {
  union { unsigned u; float f; } v; v.u = ((unsigned)b) << 16; return v.f;
}
__device__ __forceinline__ void hilo(float x, unsigned short& hi, unsigned short& lo) {
  hi = f2bf(x);
  lo = f2bf(x - bf2f(hi));
}

// per-batch arena layout (device-computed from Nvec)
__device__ __forceinline__ void layout(const int* __restrict__ Nvec, int b,
                                       size_t& offC0, size_t& offA, size_t& offB,
                                       int& n, int& nfp2, int& half) {
  size_t c0t = 0, at = 0, bt = 0, c0o = 0, ao = 0, bo = 0;
  n = 2; nfp2 = 2; half = 0;
#pragma unroll 1
  for (int i = 0; i < BATCH; ++i) {
    int ni = Nvec[i];
    int f = nfp2_of(ni);
    int hf = ni - f;
    size_t cs = (size_t)((hf + 127) & ~127) << 12;
    size_t as = (size_t)(f >> 1) << 12;
    size_t bs = (size_t)(f >> 2) << 12;
    if (i < b) { c0o += cs; ao += as; bo += bs; }
    if (i == b) { n = ni; nfp2 = f; half = hf; }
    c0t += cs; at += as; bt += bs;
  }
  offC0 = (size_t)WGLOB_SZ + c0o;
  offA = (size_t)WGLOB_SZ + c0t + ao;
  offB = (size_t)WGLOB_SZ + c0t + at + bo;
}

__device__ __forceinline__ void gload16(const void* g, void* l) {
  __builtin_amdgcn_global_load_lds((const __attribute__((address_space(1))) void*)g,
                                   (__attribute__((address_space(3))) void*)l, 16, 0, 0);
}

// ---------- W prep: W[o][k] fp32 -> Wglob[kc][o][hi 32bf16 | lo 32bf16] ----------
__global__ __launch_bounds__(256) void prep_w_k(const float* __restrict__ W, char* __restrict__ ws) {
  int idx = blockIdx.x * 256 + threadIdx.x;  // idx = kc*1536 + o
  if (idx >= 32 * 1536) return;
  int kc = idx / 1536;
  int o = idx - kc * 1536;
  const float* src = W + (size_t)o * KDIM + kc * 32;
  unsigned short hb[32], lb[32];
#pragma unroll
  for (int t = 0; t < 32; ++t) hilo(src[t], hb[t], lb[t]);
  uint4* d4 = (uint4*)(ws + ((size_t)idx << 7));
#pragma unroll
  for (int q = 0; q < 4; ++q) {
    uint4 v;
    v.x = (unsigned)hb[q*8+0] | ((unsigned)hb[q*8+1] << 16);
    v.y = (unsigned)hb[q*8+2] | ((unsigned)hb[q*8+3] << 16);
    v.z = (unsigned)hb[q*8+4] | ((unsigned)hb[q*8+5] << 16);
    v.w = (unsigned)hb[q*8+6] | ((unsigned)hb[q*8+7] << 16);
    d4[q] = v;
  }
#pragma unroll
  for (int q = 0; q < 4; ++q) {
    uint4 v;
    v.x = (unsigned)lb[q*8+0] | ((unsigned)lb[q*8+1] << 16);
    v.y = (unsigned)lb[q*8+2] | ((unsigned)lb[q*8+3] << 16);
    v.z = (unsigned)lb[q*8+4] | ((unsigned)lb[q*8+5] << 16);
    v.w = (unsigned)lb[q*8+6] | ((unsigned)lb[q*8+7] << 16);
    d4[4 + q] = v;
  }
}

// ---------- h reorg: coalesced read + LDS transpose ----------
__global__ __launch_bounds__(256) void reorg_h_k(const float* __restrict__ h,
                                                 const int* __restrict__ Nvec,
                                                 char* __restrict__ ws,
                                                 float* __restrict__ dout, int mode) {
  __shared__ char T[32 * 512];  // 16 KB
  const int b = blockIdx.z;
  size_t offC0, offA, offB; int n, nfp2, half;
  layout(Nvec, b, offC0, offA, offB, n, nfp2, half);
  const int tid = threadIdx.x;
  const int c0 = blockIdx.y * 64;

  if (mode == 1 && nfp2 == 1) {  // degenerate: answer is h[:, 0]
    if (blockIdx.x == 0 && tid < 64)
      dout[(size_t)b * CH + c0 + tid] = h[(size_t)b * CH * LMAX + (size_t)(c0 + tid) * LMAX];
    return;
  }

  const int d0 = blockIdx.x * 32;
  int dlo, dhi, soff;
  size_t base;
  if (mode == 0) { dlo = 0; dhi = half; soff = 0; base = offC0; }
  else { dlo = half >> 1; dhi = nfp2 >> 1; soff = half; base = offA; }
  if (d0 >= dhi || d0 + 32 <= dlo) return;

  const float* hb = h + (size_t)b * CH * LMAX;

#pragma unroll
  for (int q = 0; q < 8; ++q) {
    int id = q * 256 + tid;
    int cl = id >> 5;
    int dl = id & 31;
    int d = d0 + dl;
    bool ok = (d < dhi) && (d >= dlo);
    float2 v;
    v.x = 0.f; v.y = 0.f;
    if (ok) v = *(const float2*)(hb + (size_t)(c0 + cl) * LMAX + 2 * d + soff);
    unsigned short h0, l0_, h1, l1_;
    hilo(v.x, h0, l0_);
    hilo(v.y, h1, l1_);
    int g = cl >> 2;
    int byte_hi = dl * 512 + ((g ^ (dl & 15)) << 4) + (cl & 3) * 4;
    *(unsigned*)(T + byte_hi) = (unsigned)h0 | ((unsigned)h1 << 16);
    *(unsigned*)(T + byte_hi + 256) = (unsigned)l0_ | ((unsigned)l1_ << 16);
  }
  __syncthreads();
#pragma unroll
  for (int qq = 0; qq < 4; ++qq) {
    int gid = qq * 256 + tid;
    int dl = gid >> 5;
    int hl = (gid >> 4) & 1;
    int seg = gid & 15;
    int d = d0 + dl;
    if (d >= dhi || d < dlo) continue;
    uint4 val = *(const uint4*)(T + dl * 512 + hl * 256 + ((seg ^ (dl & 15)) << 4));
    *(uint4*)(ws + base + ((size_t)d << 12) + (hl << 11) + (size_t)c0 * 4 + seg * 16) = val;
  }
}

// ---------- one reduction level: split-bf16 MFMA GEMM + fused gate ----------
// 192x256 tile, 512 threads, 8 waves = 2 row-groups x 4 col-groups.
// Double-buffered LDS (114 KB, 1 block/CU) with T4 counted-vmcnt schedule:
// stage(kc+1) stays in flight across the barrier; never drain vmcnt to 0 in loop.
__global__ __launch_bounds__(512, 2) void mfma_level_k(const float* __restrict__ bias,
                                                       const int* __restrict__ Nvec,
                                                       char* __restrict__ ws,
                                                       float* __restrict__ dout,
                                                       int level, int tiles) {
  __shared__ char smem[114688];  // 2 x (As 24576 + Bs 32768)
  const int id = blockIdx.x;
  const int o0 = (id & 7) * 64;   // o0 group -> XCD pinned via id%8 (W slice L2-resident)
  const int r2 = id >> 3;
  const int xb = r2 % tiles;
  const int b = r2 / tiles;

  size_t offC0, offA, offB; int n, nfp2, half;
  layout(Nvec, b, offC0, offA, offB, n, nfp2, half);

  int cols;
  size_t inOff, outOff;
  if (level == 0) {
    if (half == 0) return;
    cols = half;
    inOff = offC0;
    outOff = offA;
  } else {
    int w = nfp2 >> (level - 1);
    if (w < 2) return;
    cols = w >> 1;
    inOff = (level & 1) ? offA : offB;
    outOff = (level & 1) ? offB : offA;
  }
  const bool fin = (level > 0) && ((nfp2 >> level) == 1);
  const int l0 = xb * 256;
  if (l0 >= cols) return;

  const int tid = threadIdx.x;
  const int lane = tid & 63, wid = tid >> 6;
  const int lane15 = lane & 15, lq = lane >> 4;
  const int rg = wid & 1, cg = wid >> 1;
  const char* inp = ws + inOff;

  // staging offsets (kc-independent parts)
  unsigned aoff[3]; int adst[3];
#pragma unroll
  for (int q = 0; q < 3; ++q) {
    int d = q * 8192 + tid * 16;
    int r = d >> 7;
    int p = (d >> 4) & 7;
    int o = ((r >> 6) << 9) + o0 + (r & 63);
    int g = p ^ (r & 7);
    aoff[q] = ((unsigned)o << 7) + (g << 4);
    adst[q] = q * 8192 + wid * 1024;
  }
  unsigned boff[4]; int bdst[4];
#pragma unroll
  for (int q = 0; q < 4; ++q) {
    int d = q * 8192 + tid * 16;
    int l = d >> 7;
    int p = (d >> 4) & 7;
    int lc = l0 + l; if (lc > cols - 1) lc = cols - 1;
    int g = p ^ (l & 7);
    boff[q] = ((unsigned)lc << 12) + ((unsigned)(g >> 2) << 11) + ((g & 3) << 4);
    bdst[q] = q * 8192 + wid * 1024;
  }

#define STAGE(kc, sel) do {                                                  \
    char* Ab = smem + (sel) * 57344;                                         \
    char* Bb = Ab + 24576;                                                   \
    unsigned ka = (unsigned)(kc) * (1536u << 7);                             \
    unsigned kb = (unsigned)(kc) << 6;                                       \
    _Pragma("unroll") for (int q = 0; q < 3; ++q)                            \
      gload16(ws + ka + aoff[q], Ab + adst[q]);                              \
    _Pragma("unroll") for (int q = 0; q < 4; ++q)                            \
      gload16(inp + kb + boff[q], Bb + bdst[q]);                             \
  } while (0)

#define COMPUTE(sel) do {                                                    \
    const char* Asb = smem + (sel) * 57344;                                  \
    const char* Bsb = Asb + 24576;                                           \
    __builtin_amdgcn_s_setprio(1);                                           \
    s8v bh[4], bl[4];                                                        \
    _Pragma("unroll") for (int cf = 0; cf < 4; ++cf) {                       \
      int ll = cg * 64 + cf * 16 + lane15;                                   \
      bh[cf] = *(const s8v*)(Bsb + ll * 128 + ((lq ^ (ll & 7)) << 4));       \
      bl[cf] = *(const s8v*)(Bsb + ll * 128 + (((4 + lq) ^ (ll & 7)) << 4)); \
    }                                                                        \
    _Pragma("unroll") for (int m = 0; m < 6; ++m) {                          \
      int rr = (m >> 1) * 64 + rg * 32 + (m & 1) * 16 + lane15;              \
      s8v ah = *(const s8v*)(Asb + rr * 128 + ((lq ^ (rr & 7)) << 4));       \
      s8v al = *(const s8v*)(Asb + rr * 128 + (((4 + lq) ^ (rr & 7)) << 4)); \
      _Pragma("unroll") for (int cf = 0; cf < 4; ++cf) {                     \
        acc[m][cf] = __builtin_amdgcn_mfma_f32_16x16x32_bf16(ah, bh[cf], acc[m][cf], 0, 0, 0); \
        acc[m][cf] = __builtin_amdgcn_mfma_f32_16x16x32_bf16(ah, bl[cf], acc[m][cf], 0, 0, 0); \
        acc[m][cf] = __builtin_amdgcn_mfma_f32_16x16x32_bf16(al, bh[cf], acc[m][cf], 0, 0, 0); \
      }                                                                      \
    }                                                                        \
    __builtin_amdgcn_s_setprio(0);                                           \
  } while (0)

  f4v acc[6][4];
#pragma unroll
  for (int m = 0; m < 6; ++m)
#pragma unroll
    for (int cf = 0; cf < 4; ++cf) acc[m][cf] = (f4v){0.f, 0.f, 0.f, 0.f};

  STAGE(0, 0);
#pragma unroll 1
  for (int kc = 0; kc < 31; ++kc) {
    STAGE(kc + 1, (kc + 1) & 1);   // writes buf[alt]; its last readers finished before prev trailing barrier
    asm volatile("s_waitcnt vmcnt(7)" ::: "memory");  // stage(kc) done; stage(kc+1)'s 7 stay in flight
    __builtin_amdgcn_s_barrier();
    COMPUTE(kc & 1);
    __builtin_amdgcn_s_barrier();  // readers done before next iter's STAGE overwrites buf[cur]
    __builtin_amdgcn_sched_barrier(0);
  }
  // peeled last iteration: full drain
  asm volatile("s_waitcnt vmcnt(0)" ::: "memory");
  __builtin_amdgcn_s_barrier();
  COMPUTE(1);
#undef STAGE
#undef COMPUTE

  // epilogue: gate in registers, store bf16 hi/lo pair-major (or final fp32)
  char* outp = ws + outOff;
#pragma unroll
  for (int s = 0; s < 2; ++s) {
#pragma unroll
    for (int cf = 0; cf < 4; ++cf) {
      f4v vl = acc[s][cf], vr = acc[2 + s][cf], vg = acc[4 + s][cf];
      int l = l0 + cg * 64 + cf * 16 + lane15;
      if (l >= cols) continue;
#pragma unroll
      for (int j = 0; j < 4; ++j) {
        int c = o0 + rg * 32 + s * 16 + lq * 4 + j;
        float zl = vl[j] + bias[c];
        float zr = vr[j] + bias[CH + c];
        float zg = vg[j] + bias[2 * CH + c];
        float g = 1.f / (1.f + __expf(-zg));
        float rt = 1.f - 2.f / (1.f + __expf(2.f * zr));
        float val = zl * g + rt * (1.f - g);
        if (fin) {
          if (l == 0) dout[(size_t)b * CH + c] = val;
        } else {
          unsigned short hi, lo; hilo(val, hi, lo);
          char* orow = outp + ((size_t)(l >> 1) << 12) + ((size_t)(2 * c + (l & 1)) << 1);
          *(unsigned short*)(orow) = hi;
          *(unsigned short*)(orow + 2048) = lo;
        }
      }
    }
  }
}

extern "C" void kernel_launch(void* const* d_in, const int* in_sizes, int n_in,
                              void* d_out, int out_size, void* d_ws, size_t ws_size,
                              hipStream_t stream) {
  const float* h = (const float*)d_in[0];
  const float* W = (const float*)d_in[1];
  const float* bias = (const float*)d_in[2];
  const int* Nvec = (const int*)d_in[3];
  float* dout = (float*)d_out;
  char* ws = (char*)d_ws;

  prep_w_k<<<dim3(192), 256, 0, stream>>>(W, ws);
  reorg_h_k<<<dim3(64, 8, BATCH), 256, 0, stream>>>(h, Nvec, ws, dout, 0);
  reorg_h_k<<<dim3(64, 8, BATCH), 256, 0, stream>>>(h, Nvec, ws, dout, 1);

  // level 0: max half = 952 -> 4 tiles of 256
  mfma_level_k<<<dim3(4 * 8 * BATCH), 512, 0, stream>>>(bias, Nvec, ws, dout, 0, 4);
  for (int lev = 1; lev <= 12; ++lev) {
    int colsmax = LMAX >> lev;               // worst-case cols at this level
    int tiles = (colsmax + 255) / 256; if (tiles < 1) tiles = 1;
    mfma_level_k<<<dim3(tiles * 8 * BATCH), 512, 0, stream>>>(bias, Nvec, ws, dout, lev, tiles);
  }
}

// Round 7
// 1091.484 us; speedup vs baseline: 3.6033x; 1.0106x over previous
//
#include <hip/hip_runtime.h>

#define BATCH 16
#define CH 512
#define OC 1536
#define KDIM 1024
#define LMAX 4096
#define WGLOB_SZ 6291456  // 32 kc * 1536 rows * 128 B

typedef __attribute__((ext_vector_type(8))) short s8v;
typedef __attribute__((ext_vector_type(4))) float f4v;

__device__ __forceinline__ int nfp2_of(int n) { return 1 << (31 - __clz(n)); }

__device__ __forceinline__ unsigned short f2bf(float x) {
  union { float f; unsigned u; } v; v.f = x;
  unsigned r = v.u + 0x7fffu + ((v.u >> 16) & 1u);
  return (unsigned short)(r >> 16);
}
__device__ __forceinline__ float bf2f(unsigned short b) {
  union { unsigned u; float f; } v; v.u = ((unsigned)b) << 16; return v.f;
}
__device__ __forceinline__ void hilo(float x, unsigned short& hi, unsigned short& lo) {
  hi = f2bf(x);
  lo = f2bf(x - bf2f(hi));
}

// per-batch arena layout (device-computed from Nvec)
__device__ __forceinline__ void layout(const int* __restrict__ Nvec, int b,
                                       size_t& offC0, size_t& offA, size_t& offB,
                                       int& n, int& nfp2, int& half) {
  size_t c0t = 0, at = 0, bt = 0, c0o = 0, ao = 0, bo = 0;
  n = 2; nfp2 = 2; half = 0;
#pragma unroll 1
  for (int i = 0; i < BATCH; ++i) {
    int ni = Nvec[i];
    int f = nfp2_of(ni);
    int hf = ni - f;
    size_t cs = (size_t)((hf + 127) & ~127) << 12;
    size_t as = (size_t)(f >> 1) << 12;
    size_t bs = (size_t)(f >> 2) << 12;
    if (i < b) { c0o += cs; ao += as; bo += bs; }
    if (i == b) { n = ni; nfp2 = f; half = hf; }
    c0t += cs; at += as; bt += bs;
  }
  offC0 = (size_t)WGLOB_SZ + c0o;
  offA = (size_t)WGLOB_SZ + c0t + ao;
  offB = (size_t)WGLOB_SZ + c0t + at + bo;
}

__device__ __forceinline__ void gload16(const void* g, void* l) {
  __builtin_amdgcn_global_load_lds((const __attribute__((address_space(1))) void*)g,
                                   (__attribute__((address_space(3))) void*)l, 16, 0, 0);
}

// ---------- W prep: W[o][k] fp32 -> Wglob[kc][o][hi 32bf16 | lo 32bf16] ----------
__global__ __launch_bounds__(256) void prep_w_k(const float* __restrict__ W, char* __restrict__ ws) {
  int idx = blockIdx.x * 256 + threadIdx.x;  // idx = kc*1536 + o
  if (idx >= 32 * 1536) return;
  int kc = idx / 1536;
  int o = idx - kc * 1536;
  const float* src = W + (size_t)o * KDIM + kc * 32;
  unsigned short hb[32], lb[32];
#pragma unroll
  for (int t = 0; t < 32; ++t) hilo(src[t], hb[t], lb[t]);
  uint4* d4 = (uint4*)(ws + ((size_t)idx << 7));
#pragma unroll
  for (int q = 0; q < 4; ++q) {
    uint4 v;
    v.x = (unsigned)hb[q*8+0] | ((unsigned)hb[q*8+1] << 16);
    v.y = (unsigned)hb[q*8+2] | ((unsigned)hb[q*8+3] << 16);
    v.z = (unsigned)hb[q*8+4] | ((unsigned)hb[q*8+5] << 16);
    v.w = (unsigned)hb[q*8+6] | ((unsigned)hb[q*8+7] << 16);
    d4[q] = v;
  }
#pragma unroll
  for (int q = 0; q < 4; ++q) {
    uint4 v;
    v.x = (unsigned)lb[q*8+0] | ((unsigned)lb[q*8+1] << 16);
    v.y = (unsigned)lb[q*8+2] | ((unsigned)lb[q*8+3] << 16);
    v.z = (unsigned)lb[q*8+4] | ((unsigned)lb[q*8+5] << 16);
    v.w = (unsigned)lb[q*8+6] | ((unsigned)lb[q*8+7] << 16);
    d4[4 + q] = v;
  }
}

// ---------- h reorg: coalesced read + LDS transpose ----------
__global__ __launch_bounds__(256) void reorg_h_k(const float* __restrict__ h,
                                                 const int* __restrict__ Nvec,
                                                 char* __restrict__ ws,
                                                 float* __restrict__ dout, int mode) {
  __shared__ char T[32 * 512];  // 16 KB
  const int b = blockIdx.z;
  size_t offC0, offA, offB; int n, nfp2, half;
  layout(Nvec, b, offC0, offA, offB, n, nfp2, half);
  const int tid = threadIdx.x;
  const int c0 = blockIdx.y * 64;

  if (mode == 1 && nfp2 == 1) {  // degenerate: answer is h[:, 0]
    if (blockIdx.x == 0 && tid < 64)
      dout[(size_t)b * CH + c0 + tid] = h[(size_t)b * CH * LMAX + (size_t)(c0 + tid) * LMAX];
    return;
  }

  const int d0 = blockIdx.x * 32;
  int dlo, dhi, soff;
  size_t base;
  if (mode == 0) { dlo = 0; dhi = half; soff = 0; base = offC0; }
  else { dlo = half >> 1; dhi = nfp2 >> 1; soff = half; base = offA; }
  if (d0 >= dhi || d0 + 32 <= dlo) return;

  const float* hb = h + (size_t)b * CH * LMAX;

#pragma unroll
  for (int q = 0; q < 8; ++q) {
    int id = q * 256 + tid;
    int cl = id >> 5;
    int dl = id & 31;
    int d = d0 + dl;
    bool ok = (d < dhi) && (d >= dlo);
    float2 v;
    v.x = 0.f; v.y = 0.f;
    if (ok) v = *(const float2*)(hb + (size_t)(c0 + cl) * LMAX + 2 * d + soff);
    unsigned short h0, l0_, h1, l1_;
    hilo(v.x, h0, l0_);
    hilo(v.y, h1, l1_);
    int g = cl >> 2;
    int byte_hi = dl * 512 + ((g ^ (dl & 15)) << 4) + (cl & 3) * 4;
    *(unsigned*)(T + byte_hi) = (unsigned)h0 | ((unsigned)h1 << 16);
    *(unsigned*)(T + byte_hi + 256) = (unsigned)l0_ | ((unsigned)l1_ << 16);
  }
  __syncthreads();
#pragma unroll
  for (int qq = 0; qq < 4; ++qq) {
    int gid = qq * 256 + tid;
    int dl = gid >> 5;
    int hl = (gid >> 4) & 1;
    int seg = gid & 15;
    int d = d0 + dl;
    if (d >= dhi || d < dlo) continue;
    uint4 val = *(const uint4*)(T + dl * 512 + hl * 256 + ((seg ^ (dl & 15)) << 4));
    *(uint4*)(ws + base + ((size_t)d << 12) + (hl << 11) + (size_t)c0 * 4 + seg * 16) = val;
  }
}

// ---------- one reduction level: split-bf16 MFMA GEMM + fused gate ----------
// 192x256 tile, 512 threads, 8 waves = 2 row-groups x 4 col-groups.
// Double-buffered LDS (114 KB, 1 block/CU), round-4 single-barrier pipeline.
// Block-id mapping: tile t -> XCD t%8 (id&7), o-group = (id>>3)&7 at id-stride 8,
// so the 8 blocks sharing a B col-tile run on the SAME XCD (B fetched once, L2-hit 7x).
__global__ __launch_bounds__(512, 2) void mfma_level_k(const float* __restrict__ bias,
                                                       const int* __restrict__ Nvec,
                                                       char* __restrict__ ws,
                                                       float* __restrict__ dout,
                                                       int level, int tiles) {
  __shared__ char smem[114688];  // 2 x (As 24576 + Bs 32768)
  const int id = blockIdx.x;
  const int o0 = ((id >> 3) & 7) * 64;            // o-group
  const int t = ((id >> 6) << 3) | (id & 7);      // global tile index = b*tiles + xb
  const int xb = t % tiles;
  const int b = t / tiles;
  if (b >= BATCH) return;

  size_t offC0, offA, offB; int n, nfp2, half;
  layout(Nvec, b, offC0, offA, offB, n, nfp2, half);

  int cols;
  size_t inOff, outOff;
  if (level == 0) {
    if (half == 0) return;
    cols = half;
    inOff = offC0;
    outOff = offA;
  } else {
    int w = nfp2 >> (level - 1);
    if (w < 2) return;
    cols = w >> 1;
    inOff = (level & 1) ? offA : offB;
    outOff = (level & 1) ? offB : offA;
  }
  const bool fin = (level > 0) && ((nfp2 >> level) == 1);
  const int l0 = xb * 256;
  if (l0 >= cols) return;

  const int tid = threadIdx.x;
  const int lane = tid & 63, wid = tid >> 6;
  const int lane15 = lane & 15, lq = lane >> 4;
  const int rg = wid & 1, cg = wid >> 1;
  const char* inp = ws + inOff;

  // staging offsets (kc-independent parts)
  unsigned aoff[3]; int adst[3];
#pragma unroll
  for (int q = 0; q < 3; ++q) {
    int d = q * 8192 + tid * 16;
    int r = d >> 7;
    int p = (d >> 4) & 7;
    int o = ((r >> 6) << 9) + o0 + (r & 63);
    int g = p ^ (r & 7);
    aoff[q] = ((unsigned)o << 7) + (g << 4);
    adst[q] = q * 8192 + wid * 1024;
  }
  unsigned boff[4]; int bdst[4];
#pragma unroll
  for (int q = 0; q < 4; ++q) {
    int d = q * 8192 + tid * 16;
    int l = d >> 7;
    int p = (d >> 4) & 7;
    int lc = l0 + l; if (lc > cols - 1) lc = cols - 1;
    int g = p ^ (l & 7);
    boff[q] = ((unsigned)lc << 12) + ((unsigned)(g >> 2) << 11) + ((g & 3) << 4);
    bdst[q] = q * 8192 + wid * 1024;
  }

#define STAGE(kc, sel) do {                                                  \
    char* Ab = smem + (sel) * 57344;                                         \
    char* Bb = Ab + 24576;                                                   \
    unsigned ka = (unsigned)(kc) * (1536u << 7);                             \
    unsigned kb = (unsigned)(kc) << 6;                                       \
    _Pragma("unroll") for (int q = 0; q < 3; ++q)                            \
      gload16(ws + ka + aoff[q], Ab + adst[q]);                              \
    _Pragma("unroll") for (int q = 0; q < 4; ++q)                            \
      gload16(inp + kb + boff[q], Bb + bdst[q]);                             \
  } while (0)

  f4v acc[6][4];
#pragma unroll
  for (int m = 0; m < 6; ++m)
#pragma unroll
    for (int cf = 0; cf < 4; ++cf) acc[m][cf] = (f4v){0.f, 0.f, 0.f, 0.f};

  STAGE(0, 0);
  __syncthreads();

#pragma unroll 1
  for (int kc = 0; kc < 32; ++kc) {
    const int cur = kc & 1;
    if (kc + 1 < 32) STAGE(kc + 1, cur ^ 1);  // prefetch overlaps this kc's compute
    const char* Asb = smem + cur * 57344;
    const char* Bsb = Asb + 24576;

    s8v bh[4], bl[4];
#pragma unroll
    for (int cf = 0; cf < 4; ++cf) {
      int ll = cg * 64 + cf * 16 + lane15;
      int ph = lq ^ (ll & 7);
      int pl = (4 + lq) ^ (ll & 7);
      bh[cf] = *(const s8v*)(Bsb + ll * 128 + ph * 16);
      bl[cf] = *(const s8v*)(Bsb + ll * 128 + pl * 16);
    }
#pragma unroll
    for (int m = 0; m < 6; ++m) {
      int rr = (m >> 1) * 64 + rg * 32 + (m & 1) * 16 + lane15;
      s8v ah = *(const s8v*)(Asb + rr * 128 + ((lq ^ (rr & 7)) << 4));
      s8v al = *(const s8v*)(Asb + rr * 128 + (((4 + lq) ^ (rr & 7)) << 4));
#pragma unroll
      for (int cf = 0; cf < 4; ++cf) {
        acc[m][cf] = __builtin_amdgcn_mfma_f32_16x16x32_bf16(ah, bh[cf], acc[m][cf], 0, 0, 0);
        acc[m][cf] = __builtin_amdgcn_mfma_f32_16x16x32_bf16(ah, bl[cf], acc[m][cf], 0, 0, 0);
        acc[m][cf] = __builtin_amdgcn_mfma_f32_16x16x32_bf16(al, bh[cf], acc[m][cf], 0, 0, 0);
      }
    }
    __syncthreads();
  }
#undef STAGE

  // epilogue: gate in registers, store bf16 hi/lo pair-major (or final fp32)
  char* outp = ws + outOff;
#pragma unroll
  for (int s = 0; s < 2; ++s) {
#pragma unroll
    for (int cf = 0; cf < 4; ++cf) {
      f4v vl = acc[s][cf], vr = acc[2 + s][cf], vg = acc[4 + s][cf];
      int l = l0 + cg * 64 + cf * 16 + lane15;
      if (l >= cols) continue;
#pragma unroll
      for (int j = 0; j < 4; ++j) {
        int c = o0 + rg * 32 + s * 16 + lq * 4 + j;
        float zl = vl[j] + bias[c];
        float zr = vr[j] + bias[CH + c];
        float zg = vg[j] + bias[2 * CH + c];
        float g = 1.f / (1.f + __expf(-zg));
        float rt = 1.f - 2.f / (1.f + __expf(2.f * zr));
        float val = zl * g + rt * (1.f - g);
        if (fin) {
          if (l == 0) dout[(size_t)b * CH + c] = val;
        } else {
          unsigned short hi, lo; hilo(val, hi, lo);
          char* orow = outp + ((size_t)(l >> 1) << 12) + ((size_t)(2 * c + (l & 1)) << 1);
          *(unsigned short*)(orow) = hi;
          *(unsigned short*)(orow + 2048) = lo;
        }
      }
    }
  }
}

extern "C" void kernel_launch(void* const* d_in, const int* in_sizes, int n_in,
                              void* d_out, int out_size, void* d_ws, size_t ws_size,
                              hipStream_t stream) {
  const float* h = (const float*)d_in[0];
  const float* W = (const float*)d_in[1];
  const float* bias = (const float*)d_in[2];
  const int* Nvec = (const int*)d_in[3];
  float* dout = (float*)d_out;
  char* ws = (char*)d_ws;

  prep_w_k<<<dim3(192), 256, 0, stream>>>(W, ws);
  reorg_h_k<<<dim3(64, 8, BATCH), 256, 0, stream>>>(h, Nvec, ws, dout, 0);
  reorg_h_k<<<dim3(64, 8, BATCH), 256, 0, stream>>>(h, Nvec, ws, dout, 1);

  // level 0: max half = 952 -> 4 tiles of 256
  mfma_level_k<<<dim3(4 * 8 * BATCH), 512, 0, stream>>>(bias, Nvec, ws, dout, 0, 4);
  for (int lev = 1; lev <= 12; ++lev) {
    int colsmax = LMAX >> lev;               // worst-case cols at this level
    int tiles = (colsmax + 255) / 256; if (tiles < 1) tiles = 1;
    mfma_level_k<<<dim3(tiles * 8 * BATCH), 512, 0, stream>>>(bias, Nvec, ws, dout, lev, tiles);
  }
}

// Round 8
// 716.354 us; speedup vs baseline: 5.4902x; 1.5237x over previous
//
#include <hip/hip_runtime.h>

#define BATCH 16
#define CH 512
#define OC 1536
#define KDIM 1024
#define LMAX 4096
#define WGLOB_SZ 6291456  // 32 kc * 1536 rows * 128 B (fp16 hi 64B | lo 64B)

typedef __attribute__((ext_vector_type(8))) _Float16 h8v;
typedef __attribute__((ext_vector_type(4))) float f4v;

__device__ __forceinline__ int nfp2_of(int n) { return 1 << (31 - __clz(n)); }

__device__ __forceinline__ unsigned short h2u(_Float16 h) {
  union { _Float16 h; unsigned short u; } v; v.h = h; return v.u;
}
__device__ __forceinline__ void hiloh(float x, _Float16& hi, _Float16& lo) {
  hi = (_Float16)x;
  lo = (_Float16)(x - (float)hi);
}

// per-batch arena layout (device-computed from Nvec); records are 2KB (1024 fp16)
__device__ __forceinline__ void layout(const int* __restrict__ Nvec, int b,
                                       size_t& offC0, size_t& offA, size_t& offB,
                                       int& n, int& nfp2, int& half) {
  size_t c0t = 0, at = 0, bt = 0, c0o = 0, ao = 0, bo = 0;
  n = 2; nfp2 = 2; half = 0;
#pragma unroll 1
  for (int i = 0; i < BATCH; ++i) {
    int ni = Nvec[i];
    int f = nfp2_of(ni);
    int hf = ni - f;
    size_t cs = (size_t)((hf + 127) & ~127) << 11;
    size_t as = (size_t)(f >> 1) << 11;
    size_t bs = (size_t)(f >> 2) << 11;
    if (i < b) { c0o += cs; ao += as; bo += bs; }
    if (i == b) { n = ni; nfp2 = f; half = hf; }
    c0t += cs; at += as; bt += bs;
  }
  offC0 = (size_t)WGLOB_SZ + c0o;
  offA = (size_t)WGLOB_SZ + c0t + ao;
  offB = (size_t)WGLOB_SZ + c0t + at + bo;
}

__device__ __forceinline__ void gload16(const void* g, void* l) {
  __builtin_amdgcn_global_load_lds((const __attribute__((address_space(1))) void*)g,
                                   (__attribute__((address_space(3))) void*)l, 16, 0, 0);
}

// ---------- W prep: W[o][k] fp32 -> Wglob[kc][o][hi 32 fp16 | lo 32 fp16] ----------
__global__ __launch_bounds__(256) void prep_w_k(const float* __restrict__ W, char* __restrict__ ws) {
  int idx = blockIdx.x * 256 + threadIdx.x;  // idx = kc*1536 + o
  if (idx >= 32 * 1536) return;
  int kc = idx / 1536;
  int o = idx - kc * 1536;
  const float* src = W + (size_t)o * KDIM + kc * 32;
  unsigned short hb[32], lb[32];
#pragma unroll
  for (int t = 0; t < 32; ++t) {
    _Float16 hi, lo; hiloh(src[t], hi, lo);
    hb[t] = h2u(hi); lb[t] = h2u(lo);
  }
  uint4* d4 = (uint4*)(ws + ((size_t)idx << 7));
#pragma unroll
  for (int q = 0; q < 4; ++q) {
    uint4 v;
    v.x = (unsigned)hb[q*8+0] | ((unsigned)hb[q*8+1] << 16);
    v.y = (unsigned)hb[q*8+2] | ((unsigned)hb[q*8+3] << 16);
    v.z = (unsigned)hb[q*8+4] | ((unsigned)hb[q*8+5] << 16);
    v.w = (unsigned)hb[q*8+6] | ((unsigned)hb[q*8+7] << 16);
    d4[q] = v;
  }
#pragma unroll
  for (int q = 0; q < 4; ++q) {
    uint4 v;
    v.x = (unsigned)lb[q*8+0] | ((unsigned)lb[q*8+1] << 16);
    v.y = (unsigned)lb[q*8+2] | ((unsigned)lb[q*8+3] << 16);
    v.z = (unsigned)lb[q*8+4] | ((unsigned)lb[q*8+5] << 16);
    v.w = (unsigned)lb[q*8+6] | ((unsigned)lb[q*8+7] << 16);
    d4[4 + q] = v;
  }
}

// ---------- h reorg: coalesced read + LDS transpose -> fp16 records ----------
// record[d] layout: per kc-chunk (32 k = 64B), 4 slots of 16B; slot s holds
// k-quarter (s ^ (d&3))  [bank-conflict-free ds_read with lq^(col&3) on read side]
__global__ __launch_bounds__(256) void reorg_h_k(const float* __restrict__ h,
                                                 const int* __restrict__ Nvec,
                                                 char* __restrict__ ws,
                                                 float* __restrict__ dout, int mode) {
  __shared__ char T[32 * 256];  // 8 KB: [32 d][64 ch * 2 k * 2B], groups XOR-swizzled
  const int b = blockIdx.z;
  size_t offC0, offA, offB; int n, nfp2, half;
  layout(Nvec, b, offC0, offA, offB, n, nfp2, half);
  const int tid = threadIdx.x;
  const int by = blockIdx.y;
  const int c0 = by * 64;

  if (mode == 1 && nfp2 == 1) {  // degenerate: answer is h[:, 0]
    if (blockIdx.x == 0 && tid < 64)
      dout[(size_t)b * CH + c0 + tid] = h[(size_t)b * CH * LMAX + (size_t)(c0 + tid) * LMAX];
    return;
  }

  const int d0 = blockIdx.x * 32;
  int dlo, dhi, soff;
  size_t base;
  if (mode == 0) { dlo = 0; dhi = half; soff = 0; base = offC0; }
  else { dlo = half >> 1; dhi = nfp2 >> 1; soff = half; base = offA; }
  if (d0 >= dhi || d0 + 32 <= dlo) return;

  const float* hb = h + (size_t)b * CH * LMAX;

  // phase 1: coalesced float2 read (lanes span dst cols) + fp16 convert + LDS
#pragma unroll
  for (int q = 0; q < 8; ++q) {
    int id = q * 256 + tid;
    int cl = id >> 5;          // channel within tile 0..63
    int dl = id & 31;          // dst col within tile
    int d = d0 + dl;
    bool ok = (d < dhi) && (d >= dlo);
    float2 v;
    v.x = 0.f; v.y = 0.f;
    if (ok) v = *(const float2*)(hb + (size_t)(c0 + cl) * LMAX + 2 * d + soff);
    unsigned u = (unsigned)h2u((_Float16)v.x) | ((unsigned)h2u((_Float16)v.y) << 16);
    int g = cl >> 2;
    *(unsigned*)(T + dl * 256 + ((g ^ (dl & 15)) << 4) + (cl & 3) * 4) = u;
  }
  __syncthreads();
  // phase 2: contiguous 16B stores to records (quarter-swizzled)
#pragma unroll
  for (int qq = 0; qq < 2; ++qq) {
    int gid = qq * 256 + tid;
    int dl = gid >> 4;
    int s = gid & 15;          // slot: k = 2*c0 + 8*s .. +7
    int d = d0 + dl;
    if (d >= dhi || d < dlo) continue;
    uint4 val = *(const uint4*)(T + dl * 256 + ((s ^ (dl & 15)) << 4));
    size_t dst = base + ((size_t)d << 11) + (size_t)(4 * by + (s >> 2)) * 64 +
                 (((s & 3) ^ (d & 3)) << 4);
    *(uint4*)(ws + dst) = val;
  }
}

// ---------- one reduction level: 2-pass fp16 MFMA GEMM + fused gate ----------
// 192x256 tile, 512 threads, 8 waves = 2 row-groups x 4 col-groups.
// Double-buffered LDS (80 KB), round-4 single-barrier pipeline and id mapping.
// Math: (Whi + Wlo)*xhi  -- x single fp16, W split fp16 hi/lo.
__global__ __launch_bounds__(512, 2) void mfma_level_k(const float* __restrict__ bias,
                                                       const int* __restrict__ Nvec,
                                                       char* __restrict__ ws,
                                                       float* __restrict__ dout,
                                                       int level, int tiles) {
  __shared__ char smem[81920];  // 2 x (As 24576 + Bs 16384)
  const int id = blockIdx.x;
  const int o0 = (id & 7) * 64;   // o-group pinned to XCD via id%8 (W slice L2-resident)
  const int r2 = id >> 3;
  const int xb = r2 % tiles;
  const int b = r2 / tiles;
  if (b >= BATCH) return;

  size_t offC0, offA, offB; int n, nfp2, half;
  layout(Nvec, b, offC0, offA, offB, n, nfp2, half);

  int cols;
  size_t inOff, outOff;
  if (level == 0) {
    if (half == 0) return;
    cols = half;
    inOff = offC0;
    outOff = offA;
  } else {
    int w = nfp2 >> (level - 1);
    if (w < 2) return;
    cols = w >> 1;
    inOff = (level & 1) ? offA : offB;
    outOff = (level & 1) ? offB : offA;
  }
  const bool fin = (level > 0) && ((nfp2 >> level) == 1);
  const int l0 = xb * 256;
  if (l0 >= cols) return;

  const int tid = threadIdx.x;
  const int lane = tid & 63, wid = tid >> 6;
  const int lane15 = lane & 15, lq = lane >> 4;
  const int rg = wid & 1, cg = wid >> 1;
  const char* inp = ws + inOff;

  // staging offsets (kc-independent parts)
  unsigned aoff[3]; int adst[3];
#pragma unroll
  for (int q = 0; q < 3; ++q) {
    int d = q * 8192 + tid * 16;
    int r = d >> 7;
    int p = (d >> 4) & 7;
    int o = ((r >> 6) << 9) + o0 + (r & 63);
    int g = p ^ (r & 7);
    aoff[q] = ((unsigned)o << 7) + (g << 4);
    adst[q] = q * 8192 + wid * 1024;
  }
  unsigned boff[2]; int bdst[2];
#pragma unroll
  for (int q = 0; q < 2; ++q) {
    int d = q * 8192 + tid * 16;
    int l = d >> 6;            // col within tile
    int slot = (d >> 4) & 3;
    int lc = l0 + l; if (lc > cols - 1) lc = cols - 1;
    boff[q] = ((unsigned)lc << 11) + (slot << 4);
    bdst[q] = q * 8192 + wid * 1024;
  }

#define STAGE(kc, sel) do {                                                  \
    char* Ab = smem + (sel) * 40960;                                         \
    char* Bb = Ab + 24576;                                                   \
    unsigned ka = (unsigned)(kc) * (1536u << 7);                             \
    unsigned kb = (unsigned)(kc) << 6;                                       \
    _Pragma("unroll") for (int q = 0; q < 3; ++q)                            \
      gload16(ws + ka + aoff[q], Ab + adst[q]);                              \
    _Pragma("unroll") for (int q = 0; q < 2; ++q)                            \
      gload16(inp + kb + boff[q], Bb + bdst[q]);                             \
  } while (0)

  f4v acc[6][4];
#pragma unroll
  for (int m = 0; m < 6; ++m)
#pragma unroll
    for (int cf = 0; cf < 4; ++cf) acc[m][cf] = (f4v){0.f, 0.f, 0.f, 0.f};

  STAGE(0, 0);
  __syncthreads();

#pragma unroll 1
  for (int kc = 0; kc < 32; ++kc) {
    const int cur = kc & 1;
    if (kc + 1 < 32) STAGE(kc + 1, cur ^ 1);  // prefetch overlaps this kc's compute
    const char* Asb = smem + cur * 40960;
    const char* Bsb = Asb + 24576;

    h8v bh[4];
#pragma unroll
    for (int cf = 0; cf < 4; ++cf) {
      int ll = cg * 64 + cf * 16 + lane15;
      bh[cf] = *(const h8v*)(Bsb + ll * 64 + ((lq ^ (ll & 3)) << 4));
    }
#pragma unroll
    for (int m = 0; m < 6; ++m) {
      int rr = (m >> 1) * 64 + rg * 32 + (m & 1) * 16 + lane15;
      h8v ah = *(const h8v*)(Asb + rr * 128 + ((lq ^ (rr & 7)) << 4));
      h8v al = *(const h8v*)(Asb + rr * 128 + (((4 + lq) ^ (rr & 7)) << 4));
#pragma unroll
      for (int cf = 0; cf < 4; ++cf) {
        acc[m][cf] = __builtin_amdgcn_mfma_f32_16x16x32_f16(ah, bh[cf], acc[m][cf], 0, 0, 0);
        acc[m][cf] = __builtin_amdgcn_mfma_f32_16x16x32_f16(al, bh[cf], acc[m][cf], 0, 0, 0);
      }
    }
    __syncthreads();
  }
#undef STAGE

  // epilogue: gate in registers, store fp16 record (or final fp32)
  char* outp = ws + outOff;
#pragma unroll
  for (int s = 0; s < 2; ++s) {
#pragma unroll
    for (int cf = 0; cf < 4; ++cf) {
      f4v vl = acc[s][cf], vr = acc[2 + s][cf], vg = acc[4 + s][cf];
      int l = l0 + cg * 64 + cf * 16 + lane15;
      if (l >= cols) continue;
      int P = l >> 1, par = l & 1;
#pragma unroll
      for (int j = 0; j < 4; ++j) {
        int c = o0 + rg * 32 + s * 16 + lq * 4 + j;
        float zl = vl[j] + bias[c];
        float zr = vr[j] + bias[CH + c];
        float zg = vg[j] + bias[2 * CH + c];
        float g = 1.f / (1.f + __expf(-zg));
        float rt = 1.f - 2.f / (1.f + __expf(2.f * zr));
        float val = zl * g + rt * (1.f - g);
        if (fin) {
          if (l == 0) dout[(size_t)b * CH + c] = val;
        } else {
          int k = 2 * c + par;
          size_t byte = ((size_t)P << 11) + (size_t)(k >> 5) * 64 +
                        ((((k >> 3) & 3) ^ (P & 3)) << 4) + (k & 7) * 2;
          *(unsigned short*)(outp + byte) = h2u((_Float16)val);
        }
      }
    }
  }
}

extern "C" void kernel_launch(void* const* d_in, const int* in_sizes, int n_in,
                              void* d_out, int out_size, void* d_ws, size_t ws_size,
                              hipStream_t stream) {
  const float* h = (const float*)d_in[0];
  const float* W = (const float*)d_in[1];
  const float* bias = (const float*)d_in[2];
  const int* Nvec = (const int*)d_in[3];
  float* dout = (float*)d_out;
  char* ws = (char*)d_ws;

  prep_w_k<<<dim3(192), 256, 0, stream>>>(W, ws);
  reorg_h_k<<<dim3(64, 8, BATCH), 256, 0, stream>>>(h, Nvec, ws, dout, 0);
  reorg_h_k<<<dim3(64, 8, BATCH), 256, 0, stream>>>(h, Nvec, ws, dout, 1);

  // level 0: max half = 952 -> 4 tiles of 256
  mfma_level_k<<<dim3(4 * 8 * BATCH), 512, 0, stream>>>(bias, Nvec, ws, dout, 0, 4);
  for (int lev = 1; lev <= 12; ++lev) {
    int colsmax = LMAX >> lev;               // worst-case cols at this level
    int tiles = (colsmax + 255) / 256; if (tiles < 1) tiles = 1;
    mfma_level_k<<<dim3(tiles * 8 * BATCH), 512, 0, stream>>>(bias, Nvec, ws, dout, lev, tiles);
  }
}

// Round 9
// 542.136 us; speedup vs baseline: 7.2545x; 1.3214x over previous
//
#include <hip/hip_runtime.h>

#define BATCH 16
#define CH 512
#define OC 1536
#define KDIM 1024
#define LMAX 4096
#define WGLOB_SZ 3145728  // 16 steps * 1536 rows * 128 B (fp16, 64 k per step)

typedef __attribute__((ext_vector_type(8))) _Float16 h8v;
typedef __attribute__((ext_vector_type(4))) float f4v;

__device__ __forceinline__ int nfp2_of(int n) { return 1 << (31 - __clz(n)); }

__device__ __forceinline__ unsigned short h2u(_Float16 h) {
  union { _Float16 h; unsigned short u; } v; v.h = h; return v.u;
}

// per-batch arena layout (device-computed from Nvec); records are 2KB (1024 fp16)
// record byte layout: chunk = k>>6 (128 B), slot s in chunk stores k-octant (s ^ (d&7)), 8 fp16
__device__ __forceinline__ void layout(const int* __restrict__ Nvec, int b,
                                       size_t& offC0, size_t& offA, size_t& offB,
                                       int& n, int& nfp2, int& half) {
  size_t c0t = 0, at = 0, bt = 0, c0o = 0, ao = 0, bo = 0;
  n = 2; nfp2 = 2; half = 0;
#pragma unroll 1
  for (int i = 0; i < BATCH; ++i) {
    int ni = Nvec[i];
    int f = nfp2_of(ni);
    int hf = ni - f;
    size_t cs = (size_t)((hf + 127) & ~127) << 11;
    size_t as = (size_t)(f >> 1) << 11;
    size_t bs = (size_t)(f >> 2) << 11;
    if (i < b) { c0o += cs; ao += as; bo += bs; }
    if (i == b) { n = ni; nfp2 = f; half = hf; }
    c0t += cs; at += as; bt += bs;
  }
  offC0 = (size_t)WGLOB_SZ + c0o;
  offA = (size_t)WGLOB_SZ + c0t + ao;
  offB = (size_t)WGLOB_SZ + c0t + at + bo;
}

__device__ __forceinline__ void gload16(const void* g, void* l) {
  __builtin_amdgcn_global_load_lds((const __attribute__((address_space(1))) void*)g,
                                   (__attribute__((address_space(3))) void*)l, 16, 0, 0);
}

// ---------- W prep: W[o][k] fp32 -> Wglob[step][o][128 B], slot s = octant s^(o&7) ----------
__global__ __launch_bounds__(256) void prep_w_k(const float* __restrict__ W, char* __restrict__ ws) {
  int idx = blockIdx.x * 256 + threadIdx.x;  // idx = step*1536 + o
  if (idx >= 16 * 1536) return;
  int step = idx / 1536;
  int o = idx - step * 1536;
  const float* src = W + (size_t)o * KDIM + step * 64;
  unsigned short hb[64];
#pragma unroll
  for (int t = 0; t < 64; ++t) hb[t] = h2u((_Float16)src[t]);
  uint4* d4 = (uint4*)(ws + ((size_t)idx << 7));
#pragma unroll
  for (int s = 0; s < 8; ++s) {
    int oc = (s ^ (o & 7)) * 8;
    uint4 v;
    v.x = (unsigned)hb[oc + 0] | ((unsigned)hb[oc + 1] << 16);
    v.y = (unsigned)hb[oc + 2] | ((unsigned)hb[oc + 3] << 16);
    v.z = (unsigned)hb[oc + 4] | ((unsigned)hb[oc + 5] << 16);
    v.w = (unsigned)hb[oc + 6] | ((unsigned)hb[oc + 7] << 16);
    d4[s] = v;
  }
}

// ---------- h reorg: coalesced read + LDS transpose -> fp16 records ----------
__global__ __launch_bounds__(256) void reorg_h_k(const float* __restrict__ h,
                                                 const int* __restrict__ Nvec,
                                                 char* __restrict__ ws,
                                                 float* __restrict__ dout, int mode) {
  __shared__ char T[32 * 256];  // 8 KB: [32 d][16 slots of 16 B], slots XOR-swizzled
  const int b = blockIdx.z;
  size_t offC0, offA, offB; int n, nfp2, half;
  layout(Nvec, b, offC0, offA, offB, n, nfp2, half);
  const int tid = threadIdx.x;
  const int by = blockIdx.y;
  const int c0 = by * 64;

  if (mode == 1 && nfp2 == 1) {  // degenerate: answer is h[:, 0]
    if (blockIdx.x == 0 && tid < 64)
      dout[(size_t)b * CH + c0 + tid] = h[(size_t)b * CH * LMAX + (size_t)(c0 + tid) * LMAX];
    return;
  }

  const int d0 = blockIdx.x * 32;
  int dlo, dhi, soff;
  size_t base;
  if (mode == 0) { dlo = 0; dhi = half; soff = 0; base = offC0; }
  else { dlo = half >> 1; dhi = nfp2 >> 1; soff = half; base = offA; }
  if (d0 >= dhi || d0 + 32 <= dlo) return;

  const float* hb = h + (size_t)b * CH * LMAX;

  // phase 1: coalesced float2 read (lanes span dst cols) + fp16 convert + LDS
#pragma unroll
  for (int q = 0; q < 8; ++q) {
    int id = q * 256 + tid;
    int cl = id >> 5;          // channel within tile 0..63
    int dl = id & 31;          // dst col within tile
    int d = d0 + dl;
    bool ok = (d < dhi) && (d >= dlo);
    float2 v;
    v.x = 0.f; v.y = 0.f;
    if (ok) v = *(const float2*)(hb + (size_t)(c0 + cl) * LMAX + 2 * d + soff);
    unsigned u = (unsigned)h2u((_Float16)v.x) | ((unsigned)h2u((_Float16)v.y) << 16);
    int g = cl >> 2;
    *(unsigned*)(T + dl * 256 + ((g ^ (dl & 15)) << 4) + (cl & 3) * 4) = u;
  }
  __syncthreads();
  // phase 2: contiguous 16B stores to records
  // T slot s of col d = k-octet [2c0+8s, 2c0+8s+8): chunk 2by+(s>>3), octant s&7
#pragma unroll
  for (int qq = 0; qq < 2; ++qq) {
    int gid = qq * 256 + tid;
    int dl = gid >> 4;
    int s = gid & 15;
    int d = d0 + dl;
    if (d >= dhi || d < dlo) continue;
    uint4 val = *(const uint4*)(T + dl * 256 + ((s ^ (dl & 15)) << 4));
    size_t dst = base + ((size_t)d << 11) + (size_t)((2 * by + (s >> 3)) << 7) +
                 (((s & 7) ^ (d & 7)) << 4);
    *(uint4*)(ws + dst) = val;
  }
}

// ---------- one reduction level: single-pass fp16 MFMA GEMM + fused gate ----------
// 192x256 tile, 512 threads, 8 waves = 2 row-groups x 4 col-groups.
// BK=64 (16 steps), double-buffered LDS (114 KB), round-4 pipeline & id mapping.
__global__ __launch_bounds__(512, 2) void mfma_level_k(const float* __restrict__ bias,
                                                       const int* __restrict__ Nvec,
                                                       char* __restrict__ ws,
                                                       float* __restrict__ dout,
                                                       int level, int tiles) {
  __shared__ char smem[114688];  // 2 x (As 24576 + Bs 32768)
  const int id = blockIdx.x;
  const int o0 = (id & 7) * 64;   // o-group pinned to XCD via id%8 (W slice L2-resident)
  const int r2 = id >> 3;
  const int xb = r2 % tiles;
  const int b = r2 / tiles;
  if (b >= BATCH) return;

  size_t offC0, offA, offB; int n, nfp2, half;
  layout(Nvec, b, offC0, offA, offB, n, nfp2, half);

  int cols;
  size_t inOff, outOff;
  if (level == 0) {
    if (half == 0) return;
    cols = half;
    inOff = offC0;
    outOff = offA;
  } else {
    int w = nfp2 >> (level - 1);
    if (w < 2) return;
    cols = w >> 1;
    inOff = (level & 1) ? offA : offB;
    outOff = (level & 1) ? offB : offA;
  }
  const bool fin = (level > 0) && ((nfp2 >> level) == 1);
  const int l0 = xb * 256;
  if (l0 >= cols) return;

  const int tid = threadIdx.x;
  const int lane = tid & 63, wid = tid >> 6;
  const int lane15 = lane & 15, lq = lane >> 4;
  const int rg = wid & 1, cg = wid >> 1;
  const char* inp = ws + inOff;

  // staging offsets (step-independent parts); LDS layouts mirror global slot order
  unsigned aoff[3]; int adst[3];
#pragma unroll
  for (int q = 0; q < 3; ++q) {
    int d = q * 8192 + tid * 16;
    int r = d >> 7;                               // tile row 0..191
    int p = d & 127;                              // byte within 128-B row
    int o = ((r >> 6) << 9) + o0 + (r & 63);      // global output row
    aoff[q] = ((unsigned)o << 7) + p;
    adst[q] = q * 8192 + wid * 1024;
  }
  unsigned boff[4]; int bdst[4];
#pragma unroll
  for (int q = 0; q < 4; ++q) {
    int d = q * 8192 + tid * 16;
    int l = d >> 7;                               // col within tile
    int p = d & 127;
    int lc = l0 + l; if (lc > cols - 1) lc = cols - 1;
    boff[q] = ((unsigned)lc << 11) + p;
    bdst[q] = q * 8192 + wid * 1024;
  }

#define STAGE(st, sel) do {                                                  \
    char* Ab = smem + (sel) * 57344;                                         \
    char* Bb = Ab + 24576;                                                   \
    unsigned ka = (unsigned)(st) * 196608u;                                  \
    unsigned kb = (unsigned)(st) << 7;                                       \
    _Pragma("unroll") for (int q = 0; q < 3; ++q)                            \
      gload16(ws + ka + aoff[q], Ab + adst[q]);                              \
    _Pragma("unroll") for (int q = 0; q < 4; ++q)                            \
      gload16(inp + kb + boff[q], Bb + bdst[q]);                             \
  } while (0)

  f4v acc[6][4];
#pragma unroll
  for (int m = 0; m < 6; ++m)
#pragma unroll
    for (int cf = 0; cf < 4; ++cf) acc[m][cf] = (f4v){0.f, 0.f, 0.f, 0.f};

  STAGE(0, 0);
  __syncthreads();

#pragma unroll 1
  for (int st = 0; st < 16; ++st) {
    const int cur = st & 1;
    if (st + 1 < 16) STAGE(st + 1, cur ^ 1);  // prefetch overlaps this step's compute
    const char* Asb = smem + cur * 57344;
    const char* Bsb = Asb + 24576;

#pragma unroll
    for (int s2 = 0; s2 < 2; ++s2) {
      const int oct = (s2 << 2) | lq;           // k-octant within the 64-k step
      h8v bh[4];
#pragma unroll
      for (int cf = 0; cf < 4; ++cf) {
        int ll = cg * 64 + cf * 16 + lane15;
        bh[cf] = *(const h8v*)(Bsb + ll * 128 + ((oct ^ (ll & 7)) << 4));
      }
#pragma unroll
      for (int m = 0; m < 6; ++m) {
        int rr = (m >> 1) * 64 + rg * 32 + (m & 1) * 16 + lane15;
        h8v ah = *(const h8v*)(Asb + rr * 128 + ((oct ^ (rr & 7)) << 4));
#pragma unroll
        for (int cf = 0; cf < 4; ++cf)
          acc[m][cf] = __builtin_amdgcn_mfma_f32_16x16x32_f16(ah, bh[cf], acc[m][cf], 0, 0, 0);
      }
    }
    __syncthreads();
  }
#undef STAGE

  // epilogue: gate in registers, store fp16 record (or final fp32)
  char* outp = ws + outOff;
#pragma unroll
  for (int s = 0; s < 2; ++s) {
#pragma unroll
    for (int cf = 0; cf < 4; ++cf) {
      f4v vl = acc[s][cf], vr = acc[2 + s][cf], vg = acc[4 + s][cf];
      int l = l0 + cg * 64 + cf * 16 + lane15;
      if (l >= cols) continue;
      int P = l >> 1, par = l & 1;
#pragma unroll
      for (int j = 0; j < 4; ++j) {
        int c = o0 + rg * 32 + s * 16 + lq * 4 + j;
        float zl = vl[j] + bias[c];
        float zr = vr[j] + bias[CH + c];
        float zg = vg[j] + bias[2 * CH + c];
        float g = 1.f / (1.f + __expf(-zg));
        float rt = 1.f - 2.f / (1.f + __expf(2.f * zr));
        float val = zl * g + rt * (1.f - g);
        if (fin) {
          if (l == 0) dout[(size_t)b * CH + c] = val;
        } else {
          int k = 2 * c + par;
          size_t byte = ((size_t)P << 11) + (size_t)((k >> 6) << 7) +
                        ((((k >> 3) & 7) ^ (P & 7)) << 4) + ((k & 7) << 1);
          *(unsigned short*)(outp + byte) = h2u((_Float16)val);
        }
      }
    }
  }
}

extern "C" void kernel_launch(void* const* d_in, const int* in_sizes, int n_in,
                              void* d_out, int out_size, void* d_ws, size_t ws_size,
                              hipStream_t stream) {
  const float* h = (const float*)d_in[0];
  const float* W = (const float*)d_in[1];
  const float* bias = (const float*)d_in[2];
  const int* Nvec = (const int*)d_in[3];
  float* dout = (float*)d_out;
  char* ws = (char*)d_ws;

  prep_w_k<<<dim3(96), 256, 0, stream>>>(W, ws);
  reorg_h_k<<<dim3(64, 8, BATCH), 256, 0, stream>>>(h, Nvec, ws, dout, 0);
  reorg_h_k<<<dim3(64, 8, BATCH), 256, 0, stream>>>(h, Nvec, ws, dout, 1);

  // level 0: max half = 952 -> 4 tiles of 256
  mfma_level_k<<<dim3(4 * 8 * BATCH), 512, 0, stream>>>(bias, Nvec, ws, dout, 0, 4);
  for (int lev = 1; lev <= 12; ++lev) {
    int colsmax = LMAX >> lev;               // worst-case cols at this level
    int tiles = (colsmax + 255) / 256; if (tiles < 1) tiles = 1;
    mfma_level_k<<<dim3(tiles * 8 * BATCH), 512, 0, stream>>>(bias, Nvec, ws, dout, lev, tiles);
  }
}

// Round 10
// 531.890 us; speedup vs baseline: 7.3943x; 1.0193x over previous
//
#include <hip/hip_runtime.h>

#define BATCH 16
#define CH 512
#define OC 1536
#define KDIM 1024
#define LMAX 4096
#define WGLOB_SZ 3145728  // 16 steps * 1536 rows * 128 B (fp16, 64 k per step)

typedef __attribute__((ext_vector_type(8))) _Float16 h8v;
typedef __attribute__((ext_vector_type(4))) float f4v;

__device__ __forceinline__ int nfp2_of(int n) { return 1 << (31 - __clz(n)); }

__device__ __forceinline__ unsigned short h2u(_Float16 h) {
  union { _Float16 h; unsigned short u; } v; v.h = h; return v.u;
}

// per-batch arena layout (device-computed from Nvec); records are 2KB (1024 fp16)
// record byte layout: chunk = k>>6 (128 B), slot s in chunk stores k-octant (s ^ (d&7)), 8 fp16
__device__ __forceinline__ void layout(const int* __restrict__ Nvec, int b,
                                       size_t& offC0, size_t& offA, size_t& offB,
                                       int& n, int& nfp2, int& half) {
  size_t c0t = 0, at = 0, bt = 0, c0o = 0, ao = 0, bo = 0;
  n = 2; nfp2 = 2; half = 0;
#pragma unroll 1
  for (int i = 0; i < BATCH; ++i) {
    int ni = Nvec[i];
    int f = nfp2_of(ni);
    int hf = ni - f;
    size_t cs = (size_t)((hf + 127) & ~127) << 11;
    size_t as = (size_t)(f >> 1) << 11;
    size_t bs = (size_t)(f >> 2) << 11;
    if (i < b) { c0o += cs; ao += as; bo += bs; }
    if (i == b) { n = ni; nfp2 = f; half = hf; }
    c0t += cs; at += as; bt += bs;
  }
  offC0 = (size_t)WGLOB_SZ + c0o;
  offA = (size_t)WGLOB_SZ + c0t + ao;
  offB = (size_t)WGLOB_SZ + c0t + at + bo;
}

__device__ __forceinline__ void gload16(const void* g, void* l) {
  __builtin_amdgcn_global_load_lds((const __attribute__((address_space(1))) void*)g,
                                   (__attribute__((address_space(3))) void*)l, 16, 0, 0);
}

// ---------- W prep: W[o][k] fp32 -> Wglob[step][o][128 B], slot s = octant s^(o&7) ----------
__global__ __launch_bounds__(256) void prep_w_k(const float* __restrict__ W, char* __restrict__ ws) {
  int idx = blockIdx.x * 256 + threadIdx.x;  // idx = step*1536 + o
  if (idx >= 16 * 1536) return;
  int step = idx / 1536;
  int o = idx - step * 1536;
  const float* src = W + (size_t)o * KDIM + step * 64;
  unsigned short hb[64];
#pragma unroll
  for (int t = 0; t < 64; ++t) hb[t] = h2u((_Float16)src[t]);
  uint4* d4 = (uint4*)(ws + ((size_t)idx << 7));
#pragma unroll
  for (int s = 0; s < 8; ++s) {
    int oc = (s ^ (o & 7)) * 8;
    uint4 v;
    v.x = (unsigned)hb[oc + 0] | ((unsigned)hb[oc + 1] << 16);
    v.y = (unsigned)hb[oc + 2] | ((unsigned)hb[oc + 3] << 16);
    v.z = (unsigned)hb[oc + 4] | ((unsigned)hb[oc + 5] << 16);
    v.w = (unsigned)hb[oc + 6] | ((unsigned)hb[oc + 7] << 16);
    d4[s] = v;
  }
}

// ---------- h reorg: coalesced read + LDS transpose -> fp16 records ----------
__global__ __launch_bounds__(256) void reorg_h_k(const float* __restrict__ h,
                                                 const int* __restrict__ Nvec,
                                                 char* __restrict__ ws,
                                                 float* __restrict__ dout, int mode) {
  __shared__ char T[32 * 256];  // 8 KB: [32 d][16 slots of 16 B], slots XOR-swizzled
  const int b = blockIdx.z;
  size_t offC0, offA, offB; int n, nfp2, half;
  layout(Nvec, b, offC0, offA, offB, n, nfp2, half);
  const int tid = threadIdx.x;
  const int by = blockIdx.y;
  const int c0 = by * 64;

  if (mode == 1 && nfp2 == 1) {  // degenerate: answer is h[:, 0]
    if (blockIdx.x == 0 && tid < 64)
      dout[(size_t)b * CH + c0 + tid] = h[(size_t)b * CH * LMAX + (size_t)(c0 + tid) * LMAX];
    return;
  }

  const int d0 = blockIdx.x * 32;
  int dlo, dhi, soff;
  size_t base;
  if (mode == 0) { dlo = 0; dhi = half; soff = 0; base = offC0; }
  else { dlo = half >> 1; dhi = nfp2 >> 1; soff = half; base = offA; }
  if (d0 >= dhi || d0 + 32 <= dlo) return;

  const float* hb = h + (size_t)b * CH * LMAX;

  // phase 1: coalesced float2 read (lanes span dst cols) + fp16 convert + LDS
#pragma unroll
  for (int q = 0; q < 8; ++q) {
    int id = q * 256 + tid;
    int cl = id >> 5;          // channel within tile 0..63
    int dl = id & 31;          // dst col within tile
    int d = d0 + dl;
    bool ok = (d < dhi) && (d >= dlo);
    float2 v;
    v.x = 0.f; v.y = 0.f;
    if (ok) v = *(const float2*)(hb + (size_t)(c0 + cl) * LMAX + 2 * d + soff);
    unsigned u = (unsigned)h2u((_Float16)v.x) | ((unsigned)h2u((_Float16)v.y) << 16);
    int g = cl >> 2;
    *(unsigned*)(T + dl * 256 + ((g ^ (dl & 15)) << 4) + (cl & 3) * 4) = u;
  }
  __syncthreads();
  // phase 2: contiguous 16B stores to records
#pragma unroll
  for (int qq = 0; qq < 2; ++qq) {
    int gid = qq * 256 + tid;
    int dl = gid >> 4;
    int s = gid & 15;
    int d = d0 + dl;
    if (d >= dhi || d < dlo) continue;
    uint4 val = *(const uint4*)(T + dl * 256 + ((s ^ (dl & 15)) << 4));
    size_t dst = base + ((size_t)d << 11) + (size_t)((2 * by + (s >> 3)) << 7) +
                 (((s & 7) ^ (d & 7)) << 4);
    *(uint4*)(ws + dst) = val;
  }
}

// ---------- one reduction level: single-pass fp16 MFMA GEMM + fused gate ----------
// 192x256 tile, 512 threads, 8 waves = 2 row-groups x 4 col-groups. BK=64 (16 steps).
// Counted-vmcnt pipeline (T4): A double-buffered (1-step prefetch, L2-resident W),
// B triple-buffered (2-step prefetch covers cross-XCD latency). ONE barrier per step;
// loads stay in flight across it (vmcnt(4)). lgkmcnt(0) before barrier closes the
// ds_read-vs-overwrite race; memory-clobber asm after barrier blocks ds_read hoist.
__global__ __launch_bounds__(512, 2) void mfma_level_k(const float* __restrict__ bias,
                                                       const int* __restrict__ Nvec,
                                                       char* __restrict__ ws,
                                                       float* __restrict__ dout,
                                                       int level, int tiles) {
  __shared__ char smem[147456];  // A: 2 x 24576, B: 3 x 32768
  const int id = blockIdx.x;
  const int o0 = (id & 7) * 64;   // o-group pinned to XCD via id%8 (W slice L2-resident)
  const int r2 = id >> 3;
  const int xb = r2 % tiles;
  const int b = r2 / tiles;
  if (b >= BATCH) return;

  size_t offC0, offA, offB; int n, nfp2, half;
  layout(Nvec, b, offC0, offA, offB, n, nfp2, half);

  int cols;
  size_t inOff, outOff;
  if (level == 0) {
    if (half == 0) return;
    cols = half;
    inOff = offC0;
    outOff = offA;
  } else {
    int w = nfp2 >> (level - 1);
    if (w < 2) return;
    cols = w >> 1;
    inOff = (level & 1) ? offA : offB;
    outOff = (level & 1) ? offB : offA;
  }
  const bool fin = (level > 0) && ((nfp2 >> level) == 1);
  const int l0 = xb * 256;
  if (l0 >= cols) return;

  const int tid = threadIdx.x;
  const int lane = tid & 63, wid = tid >> 6;
  const int lane15 = lane & 15, lq = lane >> 4;
  const int rg = wid & 1, cg = wid >> 1;
  const char* inp = ws + inOff;

  // staging offsets (step-independent parts); LDS layouts mirror global slot order
  unsigned aoff[3]; int adst[3];
#pragma unroll
  for (int q = 0; q < 3; ++q) {
    int d = q * 8192 + tid * 16;
    int r = d >> 7;                               // tile row 0..191
    int p = d & 127;                              // byte within 128-B row
    int o = ((r >> 6) << 9) + o0 + (r & 63);      // global output row
    aoff[q] = ((unsigned)o << 7) + p;
    adst[q] = q * 8192 + wid * 1024;
  }
  unsigned boff[4]; int bdst[4];
#pragma unroll
  for (int q = 0; q < 4; ++q) {
    int d = q * 8192 + tid * 16;
    int l = d >> 7;                               // col within tile
    int p = d & 127;
    int lc = l0 + l; if (lc > cols - 1) lc = cols - 1;
    boff[q] = ((unsigned)lc << 11) + p;
    bdst[q] = q * 8192 + wid * 1024;
  }

#define STAGE_A(st, sel) do {                                                \
    char* Ab = smem + (sel) * 24576;                                         \
    unsigned ka = (unsigned)(st) * 196608u;                                  \
    _Pragma("unroll") for (int q = 0; q < 3; ++q)                            \
      gload16(ws + ka + aoff[q], Ab + adst[q]);                              \
  } while (0)
#define STAGE_B(st, sel) do {                                                \
    char* Bb = smem + 49152 + (sel) * 32768;                                 \
    unsigned kb = (unsigned)(st) << 7;                                       \
    _Pragma("unroll") for (int q = 0; q < 4; ++q)                            \
      gload16(inp + kb + boff[q], Bb + bdst[q]);                             \
  } while (0)

  f4v acc[6][4];
#pragma unroll
  for (int m = 0; m < 6; ++m)
#pragma unroll
    for (int cf = 0; cf < 4; ++cf) acc[m][cf] = (f4v){0.f, 0.f, 0.f, 0.f};

  // prologue: A(0), B(0), B(1) in flight
  STAGE_A(0, 0);
  STAGE_B(0, 0);
  STAGE_B(1, 1);

  int rb = 0;          // B read buffer (st % 3)
  int wb = 2;          // B write buffer ((st+2) % 3)
#pragma unroll 1
  for (int st = 0; st < 16; ++st) {
    // step boundary: A(st) & B(st) landed; A(st+1)/B(st+2) (4 newest) stay in flight.
    // lgkmcnt(0): all our ds_reads of the previous step retired before anyone
    // overwrites that A buffer after the barrier.
    if (st < 15) asm volatile("s_waitcnt vmcnt(4) lgkmcnt(0)" ::: "memory");
    else         asm volatile("s_waitcnt vmcnt(0) lgkmcnt(0)" ::: "memory");
    __builtin_amdgcn_s_barrier();
    asm volatile("" ::: "memory");   // block ds_read hoist above the barrier

    const char* Asb = smem + (st & 1) * 24576;
    const char* Bsb = smem + 49152 + rb * 32768;

#pragma unroll
    for (int s2 = 0; s2 < 2; ++s2) {
      const int oct = (s2 << 2) | lq;           // k-octant within the 64-k step
      h8v bh[4];
#pragma unroll
      for (int cf = 0; cf < 4; ++cf) {
        int ll = cg * 64 + cf * 16 + lane15;
        bh[cf] = *(const h8v*)(Bsb + ll * 128 + ((oct ^ (ll & 7)) << 4));
      }
      h8v ah[6];
#pragma unroll
      for (int m = 0; m < 6; ++m) {
        int rr = (m >> 1) * 64 + rg * 32 + (m & 1) * 16 + lane15;
        ah[m] = *(const h8v*)(Asb + rr * 128 + ((oct ^ (rr & 7)) << 4));
      }
      // issue next stages under this phase's MFMAs
      if (s2 == 0) { if (st + 1 < 16) STAGE_A(st + 1, (st + 1) & 1); }
      else         { if (st + 2 < 16) STAGE_B(st + 2, wb); }
      __builtin_amdgcn_s_setprio(1);
#pragma unroll
      for (int m = 0; m < 6; ++m)
#pragma unroll
        for (int cf = 0; cf < 4; ++cf)
          acc[m][cf] = __builtin_amdgcn_mfma_f32_16x16x32_f16(ah[m], bh[cf], acc[m][cf], 0, 0, 0);
      __builtin_amdgcn_s_setprio(0);
    }
    rb = (rb == 2) ? 0 : rb + 1;
    wb = (wb == 2) ? 0 : wb + 1;
  }
#undef STAGE_A
#undef STAGE_B

  // epilogue: gate in registers, store fp16 record (or final fp32)
  char* outp = ws + outOff;
#pragma unroll
  for (int s = 0; s < 2; ++s) {
#pragma unroll
    for (int cf = 0; cf < 4; ++cf) {
      f4v vl = acc[s][cf], vr = acc[2 + s][cf], vg = acc[4 + s][cf];
      int l = l0 + cg * 64 + cf * 16 + lane15;
      if (l >= cols) continue;
      int P = l >> 1, par = l & 1;
#pragma unroll
      for (int j = 0; j < 4; ++j) {
        int c = o0 + rg * 32 + s * 16 + lq * 4 + j;
        float zl = vl[j] + bias[c];
        float zr = vr[j] + bias[CH + c];
        float zg = vg[j] + bias[2 * CH + c];
        float g = 1.f / (1.f + __expf(-zg));
        float rt = 1.f - 2.f / (1.f + __expf(2.f * zr));
        float val = zl * g + rt * (1.f - g);
        if (fin) {
          if (l == 0) dout[(size_t)b * CH + c] = val;
        } else {
          int k = 2 * c + par;
          size_t byte = ((size_t)P << 11) + (size_t)((k >> 6) << 7) +
                        ((((k >> 3) & 7) ^ (P & 7)) << 4) + ((k & 7) << 1);
          *(unsigned short*)(outp + byte) = h2u((_Float16)val);
        }
      }
    }
  }
}

extern "C" void kernel_launch(void* const* d_in, const int* in_sizes, int n_in,
                              void* d_out, int out_size, void* d_ws, size_t ws_size,
                              hipStream_t stream) {
  const float* h = (const float*)d_in[0];
  const float* W = (const float*)d_in[1];
  const float* bias = (const float*)d_in[2];
  const int* Nvec = (const int*)d_in[3];
  float* dout = (float*)d_out;
  char* ws = (char*)d_ws;

  prep_w_k<<<dim3(96), 256, 0, stream>>>(W, ws);
  reorg_h_k<<<dim3(64, 8, BATCH), 256, 0, stream>>>(h, Nvec, ws, dout, 0);
  reorg_h_k<<<dim3(64, 8, BATCH), 256, 0, stream>>>(h, Nvec, ws, dout, 1);

  // level 0: max half = 952 -> 4 tiles of 256
  mfma_level_k<<<dim3(4 * 8 * BATCH), 512, 0, stream>>>(bias, Nvec, ws, dout, 0, 4);
  for (int lev = 1; lev <= 12; ++lev) {
    int colsmax = LMAX >> lev;               // worst-case cols at this level
    int tiles = (colsmax + 255) / 256; if (tiles < 1) tiles = 1;
    mfma_level_k<<<dim3(tiles * 8 * BATCH), 512, 0, stream>>>(bias, Nvec, ws, dout, lev, tiles);
  }
}

// Round 11
// 494.499 us; speedup vs baseline: 7.9534x; 1.0756x over previous
//
#include <hip/hip_runtime.h>

#define BATCH 16
#define CH 512
#define OC 1536
#define KDIM 1024
#define LMAX 4096
#define WGLOB_SZ 3145728  // 16 steps * 1536 rows * 128 B (fp16, 64 k per step)

typedef __attribute__((ext_vector_type(8))) _Float16 h8v;
typedef __attribute__((ext_vector_type(4))) float f4v;

__device__ __forceinline__ int nfp2_of(int n) { return 1 << (31 - __clz(n)); }

__device__ __forceinline__ unsigned short h2u(_Float16 h) {
  union { _Float16 h; unsigned short u; } v; v.h = h; return v.u;
}

// per-batch arena layout (device-computed from Nvec); records are 2KB (1024 fp16)
// record byte layout: chunk = k>>6 (128 B), slot s in chunk stores k-octant (s ^ (d&7)), 8 fp16
__device__ __forceinline__ void layout(const int* __restrict__ Nvec, int b,
                                       size_t& offC0, size_t& offA, size_t& offB,
                                       int& n, int& nfp2, int& half) {
  size_t c0t = 0, at = 0, bt = 0, c0o = 0, ao = 0, bo = 0;
  n = 2; nfp2 = 2; half = 0;
#pragma unroll 1
  for (int i = 0; i < BATCH; ++i) {
    int ni = Nvec[i];
    int f = nfp2_of(ni);
    int hf = ni - f;
    size_t cs = (size_t)((hf + 127) & ~127) << 11;
    size_t as = (size_t)(f >> 1) << 11;
    size_t bs = (size_t)(f >> 2) << 11;
    if (i < b) { c0o += cs; ao += as; bo += bs; }
    if (i == b) { n = ni; nfp2 = f; half = hf; }
    c0t += cs; at += as; bt += bs;
  }
  offC0 = (size_t)WGLOB_SZ + c0o;
  offA = (size_t)WGLOB_SZ + c0t + ao;
  offB = (size_t)WGLOB_SZ + c0t + at + bo;
}

__device__ __forceinline__ void gload16(const void* g, void* l) {
  __builtin_amdgcn_global_load_lds((const __attribute__((address_space(1))) void*)g,
                                   (__attribute__((address_space(3))) void*)l, 16, 0, 0);
}

// ---------- W prep: W[o][k] fp32 -> Wglob[step][o][128 B], slot s = octant s^(o&7) ----------
__global__ __launch_bounds__(256) void prep_w_k(const float* __restrict__ W, char* __restrict__ ws) {
  int idx = blockIdx.x * 256 + threadIdx.x;  // idx = step*1536 + o
  if (idx >= 16 * 1536) return;
  int step = idx / 1536;
  int o = idx - step * 1536;
  const float* src = W + (size_t)o * KDIM + step * 64;
  unsigned short hb[64];
#pragma unroll
  for (int t = 0; t < 64; ++t) hb[t] = h2u((_Float16)src[t]);
  uint4* d4 = (uint4*)(ws + ((size_t)idx << 7));
#pragma unroll
  for (int s = 0; s < 8; ++s) {
    int oc = (s ^ (o & 7)) * 8;
    uint4 v;
    v.x = (unsigned)hb[oc + 0] | ((unsigned)hb[oc + 1] << 16);
    v.y = (unsigned)hb[oc + 2] | ((unsigned)hb[oc + 3] << 16);
    v.z = (unsigned)hb[oc + 4] | ((unsigned)hb[oc + 5] << 16);
    v.w = (unsigned)hb[oc + 6] | ((unsigned)hb[oc + 7] << 16);
    d4[s] = v;
  }
}

// ---------- h reorg: coalesced read + LDS transpose -> fp16 records ----------
__global__ __launch_bounds__(256) void reorg_h_k(const float* __restrict__ h,
                                                 const int* __restrict__ Nvec,
                                                 char* __restrict__ ws,
                                                 float* __restrict__ dout, int mode) {
  __shared__ char T[32 * 256];  // 8 KB: [32 d][16 slots of 16 B], slots XOR-swizzled
  const int b = blockIdx.z;
  size_t offC0, offA, offB; int n, nfp2, half;
  layout(Nvec, b, offC0, offA, offB, n, nfp2, half);
  const int tid = threadIdx.x;
  const int by = blockIdx.y;
  const int c0 = by * 64;

  if (mode == 1 && nfp2 == 1) {  // degenerate: answer is h[:, 0]
    if (blockIdx.x == 0 && tid < 64)
      dout[(size_t)b * CH + c0 + tid] = h[(size_t)b * CH * LMAX + (size_t)(c0 + tid) * LMAX];
    return;
  }

  const int d0 = blockIdx.x * 32;
  int dlo, dhi, soff;
  size_t base;
  if (mode == 0) { dlo = 0; dhi = half; soff = 0; base = offC0; }
  else { dlo = half >> 1; dhi = nfp2 >> 1; soff = half; base = offA; }
  if (d0 >= dhi || d0 + 32 <= dlo) return;

  const float* hb = h + (size_t)b * CH * LMAX;

  // phase 1: coalesced float2 read (lanes span dst cols) + fp16 convert + LDS
#pragma unroll
  for (int q = 0; q < 8; ++q) {
    int id = q * 256 + tid;
    int cl = id >> 5;          // channel within tile 0..63
    int dl = id & 31;          // dst col within tile
    int d = d0 + dl;
    bool ok = (d < dhi) && (d >= dlo);
    float2 v;
    v.x = 0.f; v.y = 0.f;
    if (ok) v = *(const float2*)(hb + (size_t)(c0 + cl) * LMAX + 2 * d + soff);
    unsigned u = (unsigned)h2u((_Float16)v.x) | ((unsigned)h2u((_Float16)v.y) << 16);
    int g = cl >> 2;
    *(unsigned*)(T + dl * 256 + ((g ^ (dl & 15)) << 4) + (cl & 3) * 4) = u;
  }
  __syncthreads();
  // phase 2: contiguous 16B stores to records
#pragma unroll
  for (int qq = 0; qq < 2; ++qq) {
    int gid = qq * 256 + tid;
    int dl = gid >> 4;
    int s = gid & 15;
    int d = d0 + dl;
    if (d >= dhi || d < dlo) continue;
    uint4 val = *(const uint4*)(T + dl * 256 + ((s ^ (dl & 15)) << 4));
    size_t dst = base + ((size_t)d << 11) + (size_t)((2 * by + (s >> 3)) << 7) +
                 (((s & 7) ^ (d & 7)) << 4);
    *(uint4*)(ws + dst) = val;
  }
}

// ---------- one reduction level: single-pass fp16 MFMA GEMM + fused gate ----------
// 192x128 tile, 256 threads, 4 waves = 2 ch-groups x 2 col-groups (per-wave 96x64
// geometry identical to the proven r9 kernel). BK=64 (16 steps).
// LDS = 2 x (A 24576 + B 16384) = 80 KB exactly -> 2 blocks/CU co-resident:
// cross-block MFMA/stage overlap hides the per-step barrier drain (m114 mechanism).
__global__ __launch_bounds__(256, 2) void mfma_level_k(const float* __restrict__ bias,
                                                       const int* __restrict__ Nvec,
                                                       char* __restrict__ ws,
                                                       float* __restrict__ dout,
                                                       int level, int tiles) {
  __shared__ char smem[81920];  // A: 2 x 24576 @0, B: 2 x 16384 @49152
  const int id = blockIdx.x;
  const int o0 = (id & 7) * 64;   // o-group pinned to XCD via id%8 (W slice L2-resident)
  const int r2 = id >> 3;
  const int xb = r2 % tiles;
  const int b = r2 / tiles;
  if (b >= BATCH) return;

  size_t offC0, offA, offB; int n, nfp2, half;
  layout(Nvec, b, offC0, offA, offB, n, nfp2, half);

  int cols;
  size_t inOff, outOff;
  if (level == 0) {
    if (half == 0) return;
    cols = half;
    inOff = offC0;
    outOff = offA;
  } else {
    int w = nfp2 >> (level - 1);
    if (w < 2) return;
    cols = w >> 1;
    inOff = (level & 1) ? offA : offB;
    outOff = (level & 1) ? offB : offA;
  }
  const bool fin = (level > 0) && ((nfp2 >> level) == 1);
  const int l0 = xb * 128;
  if (l0 >= cols) return;

  const int tid = threadIdx.x;
  const int lane = tid & 63, wid = tid >> 6;
  const int lane15 = lane & 15, lq = lane >> 4;
  const int rg = wid & 1, cg = wid >> 1;   // cg in {0,1}
  const char* inp = ws + inOff;

  // staging offsets (step-independent parts); LDS layouts mirror global slot order
  unsigned aoff[6]; int adst[6];
#pragma unroll
  for (int q = 0; q < 6; ++q) {
    int d = q * 4096 + tid * 16;
    int r = d >> 7;                               // tile row 0..191
    int p = d & 127;                              // byte within 128-B row
    int o = ((r >> 6) << 9) + o0 + (r & 63);      // global output row
    aoff[q] = ((unsigned)o << 7) + p;
    adst[q] = q * 4096 + wid * 1024;
  }
  unsigned boff[4]; int bdst[4];
#pragma unroll
  for (int q = 0; q < 4; ++q) {
    int d = q * 4096 + tid * 16;
    int l = d >> 7;                               // col within tile 0..127
    int p = d & 127;
    int lc = l0 + l; if (lc > cols - 1) lc = cols - 1;
    boff[q] = ((unsigned)lc << 11) + p;
    bdst[q] = q * 4096 + wid * 1024;
  }

#define STAGE(st, sel) do {                                                  \
    char* Ab = smem + (sel) * 24576;                                         \
    char* Bb = smem + 49152 + (sel) * 16384;                                 \
    unsigned ka = (unsigned)(st) * 196608u;                                  \
    unsigned kb = (unsigned)(st) << 7;                                       \
    _Pragma("unroll") for (int q = 0; q < 6; ++q)                            \
      gload16(ws + ka + aoff[q], Ab + adst[q]);                              \
    _Pragma("unroll") for (int q = 0; q < 4; ++q)                            \
      gload16(inp + kb + boff[q], Bb + bdst[q]);                             \
  } while (0)

  f4v acc[6][4];
#pragma unroll
  for (int m = 0; m < 6; ++m)
#pragma unroll
    for (int cf = 0; cf < 4; ++cf) acc[m][cf] = (f4v){0.f, 0.f, 0.f, 0.f};

  STAGE(0, 0);
  __syncthreads();

#pragma unroll 1
  for (int st = 0; st < 16; ++st) {
    const int cur = st & 1;
    if (st + 1 < 16) STAGE(st + 1, cur ^ 1);  // prefetch overlaps this step's compute
    const char* Asb = smem + cur * 24576;
    const char* Bsb = smem + 49152 + cur * 16384;

#pragma unroll
    for (int s2 = 0; s2 < 2; ++s2) {
      const int oct = (s2 << 2) | lq;           // k-octant within the 64-k step
      h8v bh[4];
#pragma unroll
      for (int cf = 0; cf < 4; ++cf) {
        int ll = cg * 64 + cf * 16 + lane15;
        bh[cf] = *(const h8v*)(Bsb + ll * 128 + ((oct ^ (ll & 7)) << 4));
      }
#pragma unroll
      for (int m = 0; m < 6; ++m) {
        int rr = (m >> 1) * 64 + rg * 32 + (m & 1) * 16 + lane15;
        h8v ah = *(const h8v*)(Asb + rr * 128 + ((oct ^ (rr & 7)) << 4));
#pragma unroll
        for (int cf = 0; cf < 4; ++cf)
          acc[m][cf] = __builtin_amdgcn_mfma_f32_16x16x32_f16(ah, bh[cf], acc[m][cf], 0, 0, 0);
      }
    }
    __syncthreads();
  }
#undef STAGE

  // epilogue: gate in registers, store fp16 record (or final fp32)
  char* outp = ws + outOff;
#pragma unroll
  for (int s = 0; s < 2; ++s) {
#pragma unroll
    for (int cf = 0; cf < 4; ++cf) {
      f4v vl = acc[s][cf], vr = acc[2 + s][cf], vg = acc[4 + s][cf];
      int l = l0 + cg * 64 + cf * 16 + lane15;
      if (l >= cols) continue;
      int P = l >> 1, par = l & 1;
#pragma unroll
      for (int j = 0; j < 4; ++j) {
        int c = o0 + rg * 32 + s * 16 + lq * 4 + j;
        float zl = vl[j] + bias[c];
        float zr = vr[j] + bias[CH + c];
        float zg = vg[j] + bias[2 * CH + c];
        float g = 1.f / (1.f + __expf(-zg));
        float rt = 1.f - 2.f / (1.f + __expf(2.f * zr));
        float val = zl * g + rt * (1.f - g);
        if (fin) {
          if (l == 0) dout[(size_t)b * CH + c] = val;
        } else {
          int k = 2 * c + par;
          size_t byte = ((size_t)P << 11) + (size_t)((k >> 6) << 7) +
                        ((((k >> 3) & 7) ^ (P & 7)) << 4) + ((k & 7) << 1);
          *(unsigned short*)(outp + byte) = h2u((_Float16)val);
        }
      }
    }
  }
}

extern "C" void kernel_launch(void* const* d_in, const int* in_sizes, int n_in,
                              void* d_out, int out_size, void* d_ws, size_t ws_size,
                              hipStream_t stream) {
  const float* h = (const float*)d_in[0];
  const float* W = (const float*)d_in[1];
  const float* bias = (const float*)d_in[2];
  const int* Nvec = (const int*)d_in[3];
  float* dout = (float*)d_out;
  char* ws = (char*)d_ws;

  prep_w_k<<<dim3(96), 256, 0, stream>>>(W, ws);
  reorg_h_k<<<dim3(64, 8, BATCH), 256, 0, stream>>>(h, Nvec, ws, dout, 0);
  reorg_h_k<<<dim3(64, 8, BATCH), 256, 0, stream>>>(h, Nvec, ws, dout, 1);

  // level 0: max half = 952 -> 8 tiles of 128
  mfma_level_k<<<dim3(8 * 8 * BATCH), 256, 0, stream>>>(bias, Nvec, ws, dout, 0, 8);
  for (int lev = 1; lev <= 12; ++lev) {
    int colsmax = LMAX >> lev;               // worst-case cols at this level
    int tiles = (colsmax + 127) / 128; if (tiles < 1) tiles = 1;
    mfma_level_k<<<dim3(tiles * 8 * BATCH), 256, 0, stream>>>(bias, Nvec, ws, dout, lev, tiles);
  }
}